// Round 1
// baseline (4258.187 us; speedup 1.0000x reference)
//
#include <hip/hip_runtime.h>
#include <math.h>

#define N_HEADC 16
#define D_MODELC 1024
#define D_HEADC 64
#define QLENC 1024
#define BSZC 2
#define MEMLENC 1024
#define KLENC 2048
#define RLENC 2048
#define SCALEC 0.125f
#define LN_EPSC 1e-5f

// ---------------------------------------------------------------------------
// Generic tiled fp32 GEMM: C[M,1024] = A[M,1024] @ B[1024,1024] + bias
// A rows come from A0 for row < splitRow, else from A1 (row - splitRow).
// Tile 64x64, 256 threads, each thread computes a 4x4 micro-tile.
// ---------------------------------------------------------------------------
__global__ __launch_bounds__(256) void gemm_bias_kernel(
    const float* __restrict__ A0, const float* __restrict__ A1, int splitRow,
    const float* __restrict__ B, const float* __restrict__ bias,
    float* __restrict__ C)
{
    __shared__ float As[16][68];   // [kk][row]
    __shared__ float Bs[16][68];   // [kk][col]

    const int t   = threadIdx.x;
    const int tx  = t & 15;        // col group
    const int ty  = t >> 4;        // row group
    const int row0 = blockIdx.y * 64;
    const int col0 = blockIdx.x * 64;

    float acc[4][4] = {};

    for (int k0 = 0; k0 < D_MODELC; k0 += 16) {
        // --- load A tile (64 rows x 16 k) ---
        #pragma unroll
        for (int it = 0; it < 4; ++it) {
            int l  = t + 256 * it;
            int rr = l >> 4;       // 0..63
            int kk = l & 15;
            int gr = row0 + rr;
            const float* src = (gr < splitRow)
                ? (A0 + (size_t)gr * D_MODELC)
                : (A1 + (size_t)(gr - splitRow) * D_MODELC);
            As[kk][rr] = src[k0 + kk];
        }
        // --- load B tile (16 k x 64 cols) ---
        #pragma unroll
        for (int it = 0; it < 4; ++it) {
            int l  = t + 256 * it;
            int kk = l >> 6;       // 0..15
            int cc = l & 63;
            Bs[kk][cc] = B[(size_t)(k0 + kk) * D_MODELC + col0 + cc];
        }
        __syncthreads();

        #pragma unroll
        for (int kk = 0; kk < 16; ++kk) {
            float4 a4 = *(const float4*)&As[kk][ty * 4];
            float4 b4 = *(const float4*)&Bs[kk][tx * 4];
            float av[4] = {a4.x, a4.y, a4.z, a4.w};
            float bv[4] = {b4.x, b4.y, b4.z, b4.w};
            #pragma unroll
            for (int i = 0; i < 4; ++i)
                #pragma unroll
                for (int j = 0; j < 4; ++j)
                    acc[i][j] += av[i] * bv[j];
        }
        __syncthreads();
    }

    // --- epilogue: add bias, store ---
    #pragma unroll
    for (int i = 0; i < 4; ++i) {
        int row = row0 + ty * 4 + i;
        int col = col0 + tx * 4;
        float4 o;
        o.x = acc[i][0] + bias[col + 0];
        o.y = acc[i][1] + bias[col + 1];
        o.z = acc[i][2] + bias[col + 2];
        o.w = acc[i][3] + bias[col + 3];
        *(float4*)&C[(size_t)row * D_MODELC + col] = o;
    }
}

// ---------------------------------------------------------------------------
// Attention: one wave (64 lanes) per query row i, lane = head dim d.
// score_j = SCALE * ( (q+rwb)·k_j + (q+rrb)·rk[j-i+1023] ), j in [0, i+1024]
// Online softmax, PV accumulated per-lane (o holds dim d).
// Block = 256 threads = 4 waves = 4 consecutive rows. Grid (QLEN/4, BSZ*N_HEAD)
// ---------------------------------------------------------------------------
__global__ __launch_bounds__(256) void attn_kernel(
    const float* __restrict__ q, const float* __restrict__ k,
    const float* __restrict__ v, const float* __restrict__ rk,
    const float* __restrict__ rwb, const float* __restrict__ rrb,
    float* __restrict__ av)
{
    const int wave = threadIdx.x >> 6;
    const int lane = threadIdx.x & 63;
    const int i  = blockIdx.x * 4 + wave;
    const int bn = blockIdx.y;
    const int b  = bn & 1;
    const int n  = bn >> 1;

    const size_t qidx = ((size_t)i * BSZC + b) * D_MODELC + n * D_HEADC + lane;
    const float qv = q[qidx];
    const float qw = qv + rwb[n * D_HEADC + lane];
    const float qr = qv + rrb[n * D_HEADC + lane];

    float m = -INFINITY, l = 0.f, o = 0.f;
    const int jmax = i + MEMLENC;   // inclusive

    for (int j = 0; j <= jmax; ++j) {
        const int jr = j - i + (QLENC - 1);   // rel-shift index, in [0, 2047]
        const size_t kidx = ((size_t)j * BSZC + b) * D_MODELC + n * D_HEADC + lane;
        float tsum = qw * k[kidx] + qr * rk[(size_t)jr * D_MODELC + n * D_HEADC + lane];
        // butterfly reduce across 64 lanes (all lanes get the sum)
        #pragma unroll
        for (int off = 32; off > 0; off >>= 1)
            tsum += __shfl_xor(tsum, off, 64);
        const float s  = tsum * SCALEC;
        const float mn = fmaxf(m, s);
        const float c  = __expf(m - mn);
        const float p  = __expf(s - mn);
        o = o * c + p * v[kidx];
        l = l * c + p;
        m = mn;
    }
    av[qidx] = o / l;
}

// ---------------------------------------------------------------------------
// Residual + LayerNorm: one block (256 thr) per row of [qlen*bsz, 1024]
// ---------------------------------------------------------------------------
__global__ __launch_bounds__(256) void ln_kernel(
    const float* __restrict__ w, const float* __restrict__ ao,
    const float* __restrict__ g, const float* __restrict__ bb,
    float* __restrict__ out)
{
    __shared__ float red[2][4];
    const int row  = blockIdx.x;
    const int lane = threadIdx.x & 63;
    const int wv   = threadIdx.x >> 6;
    const size_t base = (size_t)row * D_MODELC;
    const int c = threadIdx.x * 4;

    float4 xw = *(const float4*)&w[base + c];
    float4 xa = *(const float4*)&ao[base + c];
    float x[4] = {xw.x + xa.x, xw.y + xa.y, xw.z + xa.z, xw.w + xa.w};

    float sum = x[0] + x[1] + x[2] + x[3];
    float ssq = x[0]*x[0] + x[1]*x[1] + x[2]*x[2] + x[3]*x[3];
    #pragma unroll
    for (int off = 32; off > 0; off >>= 1) {
        sum += __shfl_xor(sum, off, 64);
        ssq += __shfl_xor(ssq, off, 64);
    }
    if (lane == 0) { red[0][wv] = sum; red[1][wv] = ssq; }
    __syncthreads();
    sum = red[0][0] + red[0][1] + red[0][2] + red[0][3];
    ssq = red[1][0] + red[1][1] + red[1][2] + red[1][3];

    const float mu   = sum * (1.0f / D_MODELC);
    const float var  = ssq * (1.0f / D_MODELC) - mu * mu;
    const float rstd = rsqrtf(var + LN_EPSC);

    float4 o;
    float gg[4] = {g[c], g[c+1], g[c+2], g[c+3]};
    float bbv[4] = {bb[c], bb[c+1], bb[c+2], bb[c+3]};
    o.x = (x[0] - mu) * rstd * gg[0] + bbv[0];
    o.y = (x[1] - mu) * rstd * gg[1] + bbv[1];
    o.z = (x[2] - mu) * rstd * gg[2] + bbv[2];
    o.w = (x[3] - mu) * rstd * gg[3] + bbv[3];
    *(float4*)&out[base + c] = o;
}

// ---------------------------------------------------------------------------
extern "C" void kernel_launch(void* const* d_in, const int* in_sizes, int n_in,
                              void* d_out, int out_size, void* d_ws, size_t ws_size,
                              hipStream_t stream)
{
    const float* w    = (const float*)d_in[0];
    const float* r    = (const float*)d_in[1];
    const float* mems = (const float*)d_in[2];
    const float* rwb  = (const float*)d_in[3];
    const float* rrb  = (const float*)d_in[4];
    // d_in[5] = attn_mask (bool) — deterministic causal+mem pattern, computed analytically
    const float* Wq = (const float*)d_in[6];
    const float* bq = (const float*)d_in[7];
    const float* Wk = (const float*)d_in[8];
    const float* bk = (const float*)d_in[9];
    const float* Wv = (const float*)d_in[10];
    const float* bv = (const float*)d_in[11];
    const float* Wr = (const float*)d_in[12];
    const float* br = (const float*)d_in[13];
    const float* Wo = (const float*)d_in[14];
    const float* bo = (const float*)d_in[15];
    const float* ln_g = (const float*)d_in[16];
    const float* ln_b = (const float*)d_in[17];
    float* out = (float*)d_out;

    float* ws = (float*)d_ws;
    float* q   = ws;                        // 2048*1024
    float* k   = q   + (size_t)2048 * 1024; // 4096*1024
    float* v   = k   + (size_t)4096 * 1024; // 4096*1024
    float* rk  = v   + (size_t)4096 * 1024; // 2048*1024
    float* av  = rk  + (size_t)2048 * 1024; // 2048*1024
    float* ao  = av  + (size_t)2048 * 1024; // 2048*1024

    dim3 blk(256);
    const int BIG = 1 << 30;

    // q = w @ Wq + bq           [2048, 1024]
    gemm_bias_kernel<<<dim3(16, 32), blk, 0, stream>>>(w, w, BIG, Wq, bq, q);
    // k = cat @ Wk + bk         [4096, 1024]  (cat rows: mems then w)
    gemm_bias_kernel<<<dim3(16, 64), blk, 0, stream>>>(mems, w, 2048, Wk, bk, k);
    // v = cat @ Wv + bv         [4096, 1024]
    gemm_bias_kernel<<<dim3(16, 64), blk, 0, stream>>>(mems, w, 2048, Wv, bv, v);
    // rk = r @ Wr + br          [2048, 1024]
    gemm_bias_kernel<<<dim3(16, 32), blk, 0, stream>>>(r, r, BIG, Wr, br, rk);

    // attention -> av           [2048, 1024]
    attn_kernel<<<dim3(QLENC / 4, BSZC * N_HEADC), blk, 0, stream>>>(
        q, k, v, rk, rwb, rrb, av);

    // ao = av @ Wo + bo         [2048, 1024]
    gemm_bias_kernel<<<dim3(16, 32), blk, 0, stream>>>(av, av, BIG, Wo, bo, ao);

    // out = LayerNorm(w + ao)
    ln_kernel<<<dim3(QLENC * BSZC), blk, 0, stream>>>(w, ao, ln_g, ln_b, out);
}

// Round 2
// 394.259 us; speedup vs baseline: 10.8005x; 10.8005x over previous
//
#include <hip/hip_runtime.h>
#include <math.h>

#define N_HEADC 16
#define D_MODELC 1024
#define D_HEADC 64
#define QLENC 1024
#define BSZC 2
#define MEMLENC 1024
#define KLENC 2048
#define SCALEC 0.125f
#define LN_EPSC 1e-5f

typedef __attribute__((ext_vector_type(8))) short short8;
typedef __attribute__((ext_vector_type(4))) float f32x4;

#define MFMA16(a, b, c) __builtin_amdgcn_mfma_f32_16x16x32_bf16((a), (b), (c), 0, 0, 0)

__device__ inline unsigned short f2bf(float x) {
    union { float f; unsigned int u; } c; c.f = x;
    unsigned int r = c.u + 0x7FFFu + ((c.u >> 16) & 1u);
    return (unsigned short)(r >> 16);
}
__device__ inline float bf2f(short s) {
    union { unsigned int u; float f; } c; c.u = ((unsigned int)(unsigned short)s) << 16;
    return c.f;
}

// ---------------------------------------------------------------------------
// fp32 -> bf16 cast with optional split source (for cat = [mems; w])
// ---------------------------------------------------------------------------
__global__ __launch_bounds__(256) void cast_cat_kernel(
    const float* __restrict__ s0, const float* __restrict__ s1, int splitElems,
    short* __restrict__ dst)
{
    int idx = (blockIdx.x * 256 + threadIdx.x) * 8;
    const float* src = (idx < splitElems) ? (s0 + idx) : (s1 + (idx - splitElems));
    short8 o;
    #pragma unroll
    for (int e = 0; e < 8; ++e) o[e] = (short)f2bf(src[e]);
    *(short8*)(dst + idx) = o;
}

// ---------------------------------------------------------------------------
// Weight transpose+cast: W fp32 [1024][1024] -> Wt bf16 [1024][1024], Wt[n][k]=W[k][n]
// ---------------------------------------------------------------------------
__global__ __launch_bounds__(256) void tcast_w_kernel(
    const float* __restrict__ W, short* __restrict__ Wt)
{
    __shared__ short tile[64][72];
    const int t = threadIdx.x;
    const int n0 = blockIdx.x * 64, k0 = blockIdx.y * 64;
    #pragma unroll
    for (int it = 0; it < 2; ++it) {
        int idx = t + it * 256;              // 0..511
        int kl = idx >> 3, c8 = idx & 7;
        const float* src = W + (size_t)(k0 + kl) * D_MODELC + n0 + c8 * 8;
        short8 s;
        #pragma unroll
        for (int e = 0; e < 8; ++e) s[e] = (short)f2bf(src[e]);
        *(short8*)&tile[kl][c8 * 8] = s;
    }
    __syncthreads();
    #pragma unroll
    for (int it = 0; it < 2; ++it) {
        int idx = t + it * 256;
        int nl = idx >> 3, c8 = idx & 7;
        short8 s;
        #pragma unroll
        for (int e = 0; e < 8; ++e) s[e] = tile[c8 * 8 + e][nl];
        *(short8*)(Wt + (size_t)(n0 + nl) * D_MODELC + k0 + c8 * 8) = s;
    }
}

// ---------------------------------------------------------------------------
// V transpose: v_bf [4096][1024] (row=j*2+b, col=n*64+d) -> vt [b][n][d=64][j=2048]
// ---------------------------------------------------------------------------
__global__ __launch_bounds__(256) void vtrans_kernel(
    const short* __restrict__ v_bf, short* __restrict__ vt)
{
    __shared__ short tile[64][72];
    const int t = threadIdx.x;
    const int j0 = blockIdx.x * 64;
    const int bn = blockIdx.y;
    const int b = bn & 1, n = bn >> 1;
    #pragma unroll
    for (int it = 0; it < 2; ++it) {
        int idx = t + it * 256;
        int jl = idx >> 3, c8 = idx & 7;
        short8 s = *(const short8*)(v_bf + ((size_t)(j0 + jl) * 2 + b) * D_MODELC + n * 64 + c8 * 8);
        *(short8*)&tile[jl][c8 * 8] = s;
    }
    __syncthreads();
    #pragma unroll
    for (int it = 0; it < 2; ++it) {
        int idx = t + it * 256;
        int dl = idx >> 3, c8 = idx & 7;
        short8 s;
        #pragma unroll
        for (int e = 0; e < 8; ++e) s[e] = tile[c8 * 8 + e][dl];
        *(short8*)(vt + ((size_t)(b * 16 + n) * 64 + dl) * (size_t)KLENC + j0 + c8 * 8) = s;
    }
}

// ---------------------------------------------------------------------------
// qw = bf16(q + rwb), qr = bf16(q + rrb)
// ---------------------------------------------------------------------------
__global__ __launch_bounds__(256) void qwqr_kernel(
    const short* __restrict__ q, const float* __restrict__ rwb, const float* __restrict__ rrb,
    short* __restrict__ qw, short* __restrict__ qr)
{
    int idx = (blockIdx.x * 256 + threadIdx.x) * 8;
    int c = idx & (D_MODELC - 1);
    short8 qi = *(const short8*)(q + idx);
    short8 ow, orr;
    #pragma unroll
    for (int e = 0; e < 8; ++e) {
        float f = bf2f(qi[e]);
        ow[e]  = (short)f2bf(f + rwb[c + e]);
        orr[e] = (short)f2bf(f + rrb[c + e]);
    }
    *(short8*)(qw + idx) = ow;
    *(short8*)(qr + idx) = orr;
}

// ---------------------------------------------------------------------------
// bf16 MFMA GEMM: C[M,1024] = A[M,1024] @ Bt^T + bias.  Bt is [1024][1024] = B^T.
// 128x128 tile, 4 waves (2x2), each wave 64x64 = 4x4 frags of 16x16, BK=32.
// ---------------------------------------------------------------------------
__global__ __launch_bounds__(256, 2) void gemm_bf16_kernel(
    const short* __restrict__ A, const short* __restrict__ Bt,
    const float* __restrict__ bias, void* __restrict__ Cout, int f32out)
{
    __shared__ short As[128][40];
    __shared__ short Bs[128][40];
    const int t = threadIdx.x;
    const int row0 = blockIdx.y * 128, col0 = blockIdx.x * 128;
    const int lane = t & 63, wid = t >> 6;
    const int row16 = lane & 15, g8 = lane >> 4;
    const int wr = wid >> 1, wc = wid & 1;

    f32x4 acc[4][4];
    #pragma unroll
    for (int m = 0; m < 4; ++m)
        #pragma unroll
        for (int nn = 0; nn < 4; ++nn)
            acc[m][nn] = (f32x4){0.f, 0.f, 0.f, 0.f};

    for (int k0 = 0; k0 < D_MODELC; k0 += 32) {
        #pragma unroll
        for (int c = 0; c < 2; ++c) {
            int idx = t + 256 * c;
            int rr = idx >> 2, q4 = idx & 3;
            short8 a = *(const short8*)(A + (size_t)(row0 + rr) * D_MODELC + k0 + q4 * 8);
            short8 b = *(const short8*)(Bt + (size_t)(col0 + rr) * D_MODELC + k0 + q4 * 8);
            *(short8*)&As[rr][q4 * 8] = a;
            *(short8*)&Bs[rr][q4 * 8] = b;
        }
        __syncthreads();
        short8 af[4], bfr[4];
        #pragma unroll
        for (int m = 0; m < 4; ++m)
            af[m] = *(const short8*)&As[wr * 64 + m * 16 + row16][g8 * 8];
        #pragma unroll
        for (int nn = 0; nn < 4; ++nn)
            bfr[nn] = *(const short8*)&Bs[wc * 64 + nn * 16 + row16][g8 * 8];
        #pragma unroll
        for (int m = 0; m < 4; ++m)
            #pragma unroll
            for (int nn = 0; nn < 4; ++nn)
                acc[m][nn] = MFMA16(af[m], bfr[nn], acc[m][nn]);
        __syncthreads();
    }

    float bv[4];
    #pragma unroll
    for (int nn = 0; nn < 4; ++nn)
        bv[nn] = bias[col0 + wc * 64 + nn * 16 + row16];
    #pragma unroll
    for (int m = 0; m < 4; ++m) {
        #pragma unroll
        for (int nn = 0; nn < 4; ++nn) {
            int ccol = col0 + wc * 64 + nn * 16 + row16;
            #pragma unroll
            for (int reg = 0; reg < 4; ++reg) {
                int r = row0 + wr * 64 + m * 16 + g8 * 4 + reg;
                float v = acc[m][nn][reg] + bv[nn];
                if (f32out) ((float*)Cout)[(size_t)r * D_MODELC + ccol] = v;
                else        ((short*)Cout)[(size_t)r * D_MODELC + ccol] = (short)f2bf(v);
            }
        }
    }
}

// ---------------------------------------------------------------------------
// MFMA flash attention with Transformer-XL relative shift.
// One wave per 16-row q-subtile; 4 independent waves per block (no barriers).
// S[i][j] = SCALE*( (q+rwb)[i]·k[j] + (q+rrb)[i]·rk[j-i+1023] ), mask j>i+1024.
// BD computed as matmul in (i, jr) space over an 80-wide jr window, gathered
// through LDS along the row-dependent diagonal.
// ---------------------------------------------------------------------------
__global__ __launch_bounds__(256, 2) void attn_mfma_kernel(
    const short* __restrict__ qw, const short* __restrict__ qr,
    const short* __restrict__ kb, const short* __restrict__ rkb,
    const short* __restrict__ vt, short* __restrict__ av)
{
    __shared__ float bd_lds[4][16][84];
    __shared__ short p_lds[4][16][72];

    const int wave = threadIdx.x >> 6, lane = threadIdx.x & 63;
    const int row16 = lane & 15, g8 = lane >> 4;
    const int i0 = (blockIdx.x * 4 + wave) * 16;
    const int bn = blockIdx.y;
    const int b = bn & 1, n = bn >> 1;

    // Q fragments (row = i0+row16, k = ks*32 + g8*8 + e)
    short8 qwf[2], qrf[2];
    #pragma unroll
    for (int ks = 0; ks < 2; ++ks) {
        size_t off = ((size_t)(i0 + row16) * 2 + b) * D_MODELC + n * 64 + ks * 32 + g8 * 8;
        qwf[ks] = *(const short8*)(qw + off);
        qrf[ks] = *(const short8*)(qr + off);
    }

    f32x4 accO[4];
    #pragma unroll
    for (int dt = 0; dt < 4; ++dt) accO[dt] = (f32x4){0.f, 0.f, 0.f, 0.f};
    float m[4] = {-INFINITY, -INFINITY, -INFINITY, -INFINITY};
    float lsum[4] = {0.f, 0.f, 0.f, 0.f};

    const int nsteps = (i0 + 15 + MEMLENC + 64) >> 6;   // <= 32, so j stays < 2048

    for (int step = 0; step < nsteps; ++step) {
        const int j0 = step * 64;

        // ---- AC = (q+rwb) @ K^T, 4 j-tiles ----
        f32x4 ac[4];
        #pragma unroll
        for (int jt = 0; jt < 4; ++jt) {
            ac[jt] = (f32x4){0.f, 0.f, 0.f, 0.f};
            const short* kr = kb + ((size_t)(j0 + jt * 16 + row16) * 2 + b) * D_MODELC + n * 64 + g8 * 8;
            ac[jt] = MFMA16(qwf[0], *(const short8*)kr, ac[jt]);
            ac[jt] = MFMA16(qwf[1], *(const short8*)(kr + 32), ac[jt]);
        }

        // ---- BD_full over jr window [jrb, jrb+80) ----
        const int jrb = j0 - i0 + 1008;                  // >= 0 always
        f32x4 bd[5];
        #pragma unroll
        for (int rt = 0; rt < 5; ++rt) {
            bd[rt] = (f32x4){0.f, 0.f, 0.f, 0.f};
            int jr = jrb + rt * 16 + row16;
            if (jr > KLENC - 1) jr = KLENC - 1;          // masked region only
            const short* rr = rkb + (size_t)jr * D_MODELC + n * 64 + g8 * 8;
            bd[rt] = MFMA16(qrf[0], *(const short8*)rr, bd[rt]);
            bd[rt] = MFMA16(qrf[1], *(const short8*)(rr + 32), bd[rt]);
        }
        #pragma unroll
        for (int rt = 0; rt < 5; ++rt)
            #pragma unroll
            for (int e = 0; e < 4; ++e)
                bd_lds[wave][g8 * 4 + e][rt * 16 + row16] = bd[rt][e];

        // ---- combine + mask + online softmax ----
        float S[4][4];
        #pragma unroll
        for (int reg = 0; reg < 4; ++reg) {
            const int i_loc = g8 * 4 + reg;
            const int ii = i0 + i_loc;
            #pragma unroll
            for (int jt = 0; jt < 4; ++jt) {
                const int j_loc = jt * 16 + row16;
                float sv = ac[jt][reg] + bd_lds[wave][i_loc][j_loc - i_loc + 15];
                S[reg][jt] = ((j0 + j_loc) > (ii + MEMLENC)) ? -INFINITY : sv * SCALEC;
            }
        }
        float rm[4];
        #pragma unroll
        for (int reg = 0; reg < 4; ++reg)
            rm[reg] = fmaxf(fmaxf(S[reg][0], S[reg][1]), fmaxf(S[reg][2], S[reg][3]));
        #pragma unroll
        for (int off = 8; off >= 1; off >>= 1)
            #pragma unroll
            for (int reg = 0; reg < 4; ++reg)
                rm[reg] = fmaxf(rm[reg], __shfl_xor(rm[reg], off, 64));
        float sc[4];
        #pragma unroll
        for (int reg = 0; reg < 4; ++reg) {
            float mn = fmaxf(m[reg], rm[reg]);
            sc[reg] = __expf(m[reg] - mn);
            m[reg] = mn;
        }
        float P[4][4], rs[4];
        #pragma unroll
        for (int reg = 0; reg < 4; ++reg) {
            #pragma unroll
            for (int jt = 0; jt < 4; ++jt)
                P[reg][jt] = __expf(S[reg][jt] - m[reg]);
            rs[reg] = (P[reg][0] + P[reg][1]) + (P[reg][2] + P[reg][3]);
        }
        #pragma unroll
        for (int off = 8; off >= 1; off >>= 1)
            #pragma unroll
            for (int reg = 0; reg < 4; ++reg)
                rs[reg] += __shfl_xor(rs[reg], off, 64);
        #pragma unroll
        for (int reg = 0; reg < 4; ++reg)
            lsum[reg] = lsum[reg] * sc[reg] + rs[reg];
        #pragma unroll
        for (int dt = 0; dt < 4; ++dt)
            #pragma unroll
            for (int reg = 0; reg < 4; ++reg)
                accO[dt][reg] *= sc[reg];
        #pragma unroll
        for (int reg = 0; reg < 4; ++reg)
            #pragma unroll
            for (int jt = 0; jt < 4; ++jt)
                p_lds[wave][g8 * 4 + reg][jt * 16 + row16] = (short)f2bf(P[reg][jt]);

        // ---- PV: O += P @ V (V^T layout: vt[b,n][d][j]) ----
        #pragma unroll
        for (int ks2 = 0; ks2 < 2; ++ks2) {
            short8 pf = *(const short8*)&p_lds[wave][row16][ks2 * 32 + g8 * 8];
            #pragma unroll
            for (int dt = 0; dt < 4; ++dt) {
                const short* vr = vt + ((size_t)(b * 16 + n) * 64 + dt * 16 + row16) * (size_t)KLENC
                                  + j0 + ks2 * 32 + g8 * 8;
                accO[dt] = MFMA16(pf, *(const short8*)vr, accO[dt]);
            }
        }
    }

    // epilogue: divide by lsum, store bf16 (row = i*2+b, col = n*64+d)
    #pragma unroll
    for (int dt = 0; dt < 4; ++dt)
        #pragma unroll
        for (int reg = 0; reg < 4; ++reg) {
            size_t o = ((size_t)(i0 + g8 * 4 + reg) * 2 + b) * D_MODELC + n * 64 + dt * 16 + row16;
            av[o] = (short)f2bf(accO[dt][reg] / lsum[reg]);
        }
}

// ---------------------------------------------------------------------------
// Residual + LayerNorm (fp32)
// ---------------------------------------------------------------------------
__global__ __launch_bounds__(256) void ln_kernel(
    const float* __restrict__ w, const float* __restrict__ ao,
    const float* __restrict__ g, const float* __restrict__ bb,
    float* __restrict__ out)
{
    __shared__ float red[2][4];
    const int row = blockIdx.x;
    const int lane = threadIdx.x & 63;
    const int wv = threadIdx.x >> 6;
    const size_t base = (size_t)row * D_MODELC;
    const int c = threadIdx.x * 4;

    float4 xw = *(const float4*)&w[base + c];
    float4 xa = *(const float4*)&ao[base + c];
    float x[4] = {xw.x + xa.x, xw.y + xa.y, xw.z + xa.z, xw.w + xa.w};

    float sum = x[0] + x[1] + x[2] + x[3];
    float ssq = x[0]*x[0] + x[1]*x[1] + x[2]*x[2] + x[3]*x[3];
    #pragma unroll
    for (int off = 32; off > 0; off >>= 1) {
        sum += __shfl_xor(sum, off, 64);
        ssq += __shfl_xor(ssq, off, 64);
    }
    if (lane == 0) { red[0][wv] = sum; red[1][wv] = ssq; }
    __syncthreads();
    sum = red[0][0] + red[0][1] + red[0][2] + red[0][3];
    ssq = red[1][0] + red[1][1] + red[1][2] + red[1][3];

    const float mu = sum * (1.0f / D_MODELC);
    const float var = ssq * (1.0f / D_MODELC) - mu * mu;
    const float rstd = rsqrtf(var + LN_EPSC);

    float4 o;
    o.x = (x[0] - mu) * rstd * g[c] + bb[c];
    o.y = (x[1] - mu) * rstd * g[c+1] + bb[c+1];
    o.z = (x[2] - mu) * rstd * g[c+2] + bb[c+2];
    o.w = (x[3] - mu) * rstd * g[c+3] + bb[c+3];
    *(float4*)&out[base + c] = o;
}

// ---------------------------------------------------------------------------
extern "C" void kernel_launch(void* const* d_in, const int* in_sizes, int n_in,
                              void* d_out, int out_size, void* d_ws, size_t ws_size,
                              hipStream_t stream)
{
    const float* w    = (const float*)d_in[0];
    const float* r    = (const float*)d_in[1];
    const float* mems = (const float*)d_in[2];
    const float* rwb  = (const float*)d_in[3];
    const float* rrb  = (const float*)d_in[4];
    // d_in[5] = attn_mask — deterministic causal+mem pattern, handled analytically
    const float* Wq = (const float*)d_in[6];
    const float* bq = (const float*)d_in[7];
    const float* Wk = (const float*)d_in[8];
    const float* bk = (const float*)d_in[9];
    const float* Wv = (const float*)d_in[10];
    const float* bv = (const float*)d_in[11];
    const float* Wr = (const float*)d_in[12];
    const float* br = (const float*)d_in[13];
    const float* Wo = (const float*)d_in[14];
    const float* bo = (const float*)d_in[15];
    const float* ln_g = (const float*)d_in[16];
    const float* ln_b = (const float*)d_in[17];
    float* out = (float*)d_out;

    char* ws = (char*)d_ws;
    const size_t MB = 1ull << 20;
    short* cat_bf = (short*)(ws + 0 * MB);    // [4096][1024] bf16  (8 MB)
    short* r_bf   = (short*)(ws + 8 * MB);    // [2048][1024]       (4 MB)
    short* Wq_t   = (short*)(ws + 12 * MB);   // 2 MB each
    short* Wk_t   = (short*)(ws + 14 * MB);
    short* Wv_t   = (short*)(ws + 16 * MB);
    short* Wr_t   = (short*)(ws + 18 * MB);
    short* Wo_t   = (short*)(ws + 20 * MB);
    short* q_bf   = (short*)(ws + 22 * MB);   // [2048][1024] -> reused as av_bf
    short* k_bf   = (short*)(ws + 26 * MB);   // [4096][1024] (8 MB)
    short* v_bf   = (short*)(ws + 34 * MB);   // [4096][1024] (8 MB) -> reused as ao f32
    short* rk_bf  = (short*)(ws + 42 * MB);   // [2048][1024]
    short* qw_bf  = (short*)(ws + 46 * MB);
    short* qr_bf  = (short*)(ws + 50 * MB);
    short* vt     = (short*)(ws + 54 * MB);   // [2][16][64][2048] (8 MB)
    short* av_bf  = q_bf;
    float* ao     = (float*)v_bf;

    dim3 blk(256);

    // casts
    cast_cat_kernel<<<dim3(2048), blk, 0, stream>>>(mems, w, 2048 * 1024, cat_bf);
    cast_cat_kernel<<<dim3(1024), blk, 0, stream>>>(r, r, 1 << 30, r_bf);

    // weight transposes
    tcast_w_kernel<<<dim3(16, 16), blk, 0, stream>>>(Wq, Wq_t);
    tcast_w_kernel<<<dim3(16, 16), blk, 0, stream>>>(Wk, Wk_t);
    tcast_w_kernel<<<dim3(16, 16), blk, 0, stream>>>(Wv, Wv_t);
    tcast_w_kernel<<<dim3(16, 16), blk, 0, stream>>>(Wr, Wr_t);
    tcast_w_kernel<<<dim3(16, 16), blk, 0, stream>>>(Wo, Wo_t);

    // projections (q uses only the w rows of cat)
    gemm_bf16_kernel<<<dim3(8, 16), blk, 0, stream>>>(cat_bf + (size_t)2048 * 1024, Wq_t, bq, q_bf, 0);
    gemm_bf16_kernel<<<dim3(8, 32), blk, 0, stream>>>(cat_bf, Wk_t, bk, k_bf, 0);
    gemm_bf16_kernel<<<dim3(8, 32), blk, 0, stream>>>(cat_bf, Wv_t, bv, v_bf, 0);
    gemm_bf16_kernel<<<dim3(8, 16), blk, 0, stream>>>(r_bf, Wr_t, br, rk_bf, 0);

    // q + biases, V transpose
    qwqr_kernel<<<dim3(1024), blk, 0, stream>>>(q_bf, rwb, rrb, qw_bf, qr_bf);
    vtrans_kernel<<<dim3(32, 32), blk, 0, stream>>>(v_bf, vt);

    // attention
    attn_mfma_kernel<<<dim3(16, 32), blk, 0, stream>>>(qw_bf, qr_bf, k_bf, rk_bf, vt, av_bf);

    // output projection (fp32 out) + LN
    gemm_bf16_kernel<<<dim3(8, 16), blk, 0, stream>>>(av_bf, Wo_t, bo, ao, 1);
    ln_kernel<<<dim3(2048), blk, 0, stream>>>(w, ao, ln_g, ln_b, out);
}

// Round 3
// 258.668 us; speedup vs baseline: 16.4619x; 1.5242x over previous
//
#include <hip/hip_runtime.h>
#include <math.h>

#define N_HEADC 16
#define D_MODELC 1024
#define D_HEADC 64
#define QLENC 1024
#define BSZC 2
#define MEMLENC 1024
#define KLENC 2048
#define SCALEC 0.125f
#define LN_EPSC 1e-5f

typedef __attribute__((ext_vector_type(8))) short short8;
typedef __attribute__((ext_vector_type(4))) float f32x4;

#define MFMA16(a, b, c) __builtin_amdgcn_mfma_f32_16x16x32_bf16((a), (b), (c), 0, 0, 0)

__device__ inline unsigned short f2bf(float x) {
    union { float f; unsigned int u; } c; c.f = x;
    unsigned int r = c.u + 0x7FFFu + ((c.u >> 16) & 1u);
    return (unsigned short)(r >> 16);
}
__device__ inline float bf2f(short s) {
    union { unsigned int u; float f; } c; c.u = ((unsigned int)(unsigned short)s) << 16;
    return c.f;
}

// async global->LDS, 16B per lane; lds dest = wave-uniform base + lane*16
__device__ __forceinline__ void load_lds16(const short* g, short* l) {
    __builtin_amdgcn_global_load_lds(
        (const __attribute__((address_space(1))) void*)g,
        (__attribute__((address_space(3))) void*)l,
        16, 0, 0);
}

// ---------------------------------------------------------------------------
// fp32 -> bf16 cast with optional split source (for cat = [mems; w])
// ---------------------------------------------------------------------------
__global__ __launch_bounds__(256) void cast_cat_kernel(
    const float* __restrict__ s0, const float* __restrict__ s1, int splitElems,
    short* __restrict__ dst)
{
    int idx = (blockIdx.x * 256 + threadIdx.x) * 8;
    const float* src = (idx < splitElems) ? (s0 + idx) : (s1 + (idx - splitElems));
    short8 o;
    #pragma unroll
    for (int e = 0; e < 8; ++e) o[e] = (short)f2bf(src[e]);
    *(short8*)(dst + idx) = o;
}

// ---------------------------------------------------------------------------
// 5 weight transposes fused: W fp32 [1024][1024] -> Wt bf16 [n][k]
// ---------------------------------------------------------------------------
__global__ __launch_bounds__(256) void tcast5_kernel(
    const float* __restrict__ W0, const float* __restrict__ W1,
    const float* __restrict__ W2, const float* __restrict__ W3,
    const float* __restrict__ W4,
    short* __restrict__ D0, short* __restrict__ D1, short* __restrict__ D2,
    short* __restrict__ D3, short* __restrict__ D4)
{
    __shared__ short tile[64][72];
    const float* W; short* D;
    switch (blockIdx.z) {
        case 0: W = W0; D = D0; break;
        case 1: W = W1; D = D1; break;
        case 2: W = W2; D = D2; break;
        case 3: W = W3; D = D3; break;
        default: W = W4; D = D4; break;
    }
    const int t = threadIdx.x;
    const int n0 = blockIdx.x * 64, k0 = blockIdx.y * 64;
    #pragma unroll
    for (int it = 0; it < 2; ++it) {
        int idx = t + it * 256;
        int kl = idx >> 3, c8 = idx & 7;
        const float* src = W + (size_t)(k0 + kl) * D_MODELC + n0 + c8 * 8;
        short8 s;
        #pragma unroll
        for (int e = 0; e < 8; ++e) s[e] = (short)f2bf(src[e]);
        *(short8*)&tile[kl][c8 * 8] = s;
    }
    __syncthreads();
    #pragma unroll
    for (int it = 0; it < 2; ++it) {
        int idx = t + it * 256;
        int nl = idx >> 3, c8 = idx & 7;
        short8 s;
        #pragma unroll
        for (int e = 0; e < 8; ++e) s[e] = tile[c8 * 8 + e][nl];
        *(short8*)(D + (size_t)(n0 + nl) * D_MODELC + k0 + c8 * 8) = s;
    }
}

// ---------------------------------------------------------------------------
// V transpose: v_bf [4096][1024] (row=j*2+b, col=n*64+d) -> vt [b][n][d=64][j=2048]
// ---------------------------------------------------------------------------
__global__ __launch_bounds__(256) void vtrans_kernel(
    const short* __restrict__ v_bf, short* __restrict__ vt)
{
    __shared__ short tile[64][72];
    const int t = threadIdx.x;
    const int j0 = blockIdx.x * 64;
    const int bn = blockIdx.y;
    const int b = bn & 1, n = bn >> 1;
    #pragma unroll
    for (int it = 0; it < 2; ++it) {
        int idx = t + it * 256;
        int jl = idx >> 3, c8 = idx & 7;
        short8 s = *(const short8*)(v_bf + ((size_t)(j0 + jl) * 2 + b) * D_MODELC + n * 64 + c8 * 8);
        *(short8*)&tile[jl][c8 * 8] = s;
    }
    __syncthreads();
    #pragma unroll
    for (int it = 0; it < 2; ++it) {
        int idx = t + it * 256;
        int dl = idx >> 3, c8 = idx & 7;
        short8 s;
        #pragma unroll
        for (int e = 0; e < 8; ++e) s[e] = tile[c8 * 8 + e][dl];
        *(short8*)(vt + ((size_t)(b * 16 + n) * 64 + dl) * (size_t)KLENC + j0 + c8 * 8) = s;
    }
}

// ---------------------------------------------------------------------------
// Fused projection GEMMs (K, V, Q, RK) via global_load_lds, 128x128 tile, BK=32.
// grid (8, 96): by<32 K, <64 V, <80 Q (epilogue writes qw/qr), else RK.
// ---------------------------------------------------------------------------
__global__ __launch_bounds__(256, 3) void proj_gemm_kernel(
    const short* __restrict__ cat, const short* __restrict__ rin,
    const short* __restrict__ WqT, const short* __restrict__ WkT,
    const short* __restrict__ WvT, const short* __restrict__ WrT,
    const float* __restrict__ bq, const float* __restrict__ bk,
    const float* __restrict__ bv, const float* __restrict__ br,
    const float* __restrict__ rwb, const float* __restrict__ rrb,
    short* __restrict__ qw, short* __restrict__ qr,
    short* __restrict__ kb, short* __restrict__ vb, short* __restrict__ rk)
{
    __shared__ short As[128][32];
    __shared__ short Bs[128][32];

    const int lin = blockIdx.y * 8 + blockIdx.x;        // 0..767
    const int sw  = (lin & 7) * 96 + (lin >> 3);        // XCD-contiguous
    const int bx  = sw & 7;
    const int by  = sw >> 3;

    const short* A; const short* Bt; const float* bias; int yt, mode;
    if (by < 32)      { A = cat;                         Bt = WkT; bias = bk; yt = by;      mode = 0; }
    else if (by < 64) { A = cat;                         Bt = WvT; bias = bv; yt = by - 32; mode = 1; }
    else if (by < 80) { A = cat + (size_t)2048 * 1024;   Bt = WqT; bias = bq; yt = by - 64; mode = 2; }
    else              { A = rin;                         Bt = WrT; bias = br; yt = by - 80; mode = 3; }

    const int row0 = yt * 128, col0 = bx * 128;
    const int t = threadIdx.x;
    const int lane = t & 63, wid = t >> 6;
    const int row16 = lane & 15, g8 = lane >> 4;
    const int wr = wid >> 1, wc = wid & 1;

    f32x4 acc[4][4];
    #pragma unroll
    for (int m = 0; m < 4; ++m)
        #pragma unroll
        for (int nn = 0; nn < 4; ++nn)
            acc[m][nn] = (f32x4){0.f, 0.f, 0.f, 0.f};

    short* AsB = &As[0][0] + wid * 1024;     // wave chunk (2 ops x 512 shorts)
    short* BsB = &Bs[0][0] + wid * 1024;
    const short* Ag = A  + (size_t)(row0 + wid * 32 + (lane >> 2)) * D_MODELC + (lane & 3) * 8;
    const short* Bg = Bt + (size_t)(col0 + wid * 32 + (lane >> 2)) * D_MODELC + (lane & 3) * 8;

    for (int k0 = 0; k0 < D_MODELC; k0 += 32) {
        load_lds16(Ag + k0,              AsB);
        load_lds16(Ag + k0 + 16 * 1024,  AsB + 512);
        load_lds16(Bg + k0,              BsB);
        load_lds16(Bg + k0 + 16 * 1024,  BsB + 512);
        __syncthreads();
        short8 af[4], bfr[4];
        #pragma unroll
        for (int m = 0; m < 4; ++m)
            af[m] = *(const short8*)&As[wr * 64 + m * 16 + row16][g8 * 8];
        #pragma unroll
        for (int nn = 0; nn < 4; ++nn)
            bfr[nn] = *(const short8*)&Bs[wc * 64 + nn * 16 + row16][g8 * 8];
        #pragma unroll
        for (int m = 0; m < 4; ++m)
            #pragma unroll
            for (int nn = 0; nn < 4; ++nn)
                acc[m][nn] = MFMA16(af[m], bfr[nn], acc[m][nn]);
        __syncthreads();
    }

    float bvv[4], w1[4], w2[4];
    #pragma unroll
    for (int nn = 0; nn < 4; ++nn) {
        int c = col0 + wc * 64 + nn * 16 + row16;
        bvv[nn] = bias[c];
        w1[nn] = rwb[c];
        w2[nn] = rrb[c];
    }
    if (mode == 2) {
        #pragma unroll
        for (int m = 0; m < 4; ++m)
            #pragma unroll
            for (int nn = 0; nn < 4; ++nn) {
                int c = col0 + wc * 64 + nn * 16 + row16;
                #pragma unroll
                for (int reg = 0; reg < 4; ++reg) {
                    int r = row0 + wr * 64 + m * 16 + g8 * 4 + reg;
                    float v = acc[m][nn][reg] + bvv[nn];
                    qw[(size_t)r * D_MODELC + c] = (short)f2bf(v + w1[nn]);
                    qr[(size_t)r * D_MODELC + c] = (short)f2bf(v + w2[nn]);
                }
            }
    } else {
        short* C = (mode == 0) ? kb : (mode == 1) ? vb : rk;
        #pragma unroll
        for (int m = 0; m < 4; ++m)
            #pragma unroll
            for (int nn = 0; nn < 4; ++nn) {
                int c = col0 + wc * 64 + nn * 16 + row16;
                #pragma unroll
                for (int reg = 0; reg < 4; ++reg) {
                    int r = row0 + wr * 64 + m * 16 + g8 * 4 + reg;
                    C[(size_t)r * D_MODELC + c] = (short)f2bf(acc[m][nn][reg] + bvv[nn]);
                }
            }
    }
}

// ---------------------------------------------------------------------------
// Wo GEMM, split-K=2: out_kz[2048][1024] fp32 partials (bias added in LN)
// ---------------------------------------------------------------------------
__global__ __launch_bounds__(256, 3) void wo_gemm_kernel(
    const short* __restrict__ A, const short* __restrict__ Bt,
    float* __restrict__ out0, float* __restrict__ out1)
{
    __shared__ short As[128][32];
    __shared__ short Bs[128][32];
    const int kz = blockIdx.z;
    float* C = kz ? out1 : out0;
    const int row0 = blockIdx.y * 128, col0 = blockIdx.x * 128;
    const int t = threadIdx.x;
    const int lane = t & 63, wid = t >> 6;
    const int row16 = lane & 15, g8 = lane >> 4;
    const int wr = wid >> 1, wc = wid & 1;

    f32x4 acc[4][4];
    #pragma unroll
    for (int m = 0; m < 4; ++m)
        #pragma unroll
        for (int nn = 0; nn < 4; ++nn)
            acc[m][nn] = (f32x4){0.f, 0.f, 0.f, 0.f};

    short* AsB = &As[0][0] + wid * 1024;
    short* BsB = &Bs[0][0] + wid * 1024;
    const short* Ag = A  + (size_t)(row0 + wid * 32 + (lane >> 2)) * D_MODELC + (lane & 3) * 8;
    const short* Bg = Bt + (size_t)(col0 + wid * 32 + (lane >> 2)) * D_MODELC + (lane & 3) * 8;

    const int kbase = kz * 512;
    for (int k0 = kbase; k0 < kbase + 512; k0 += 32) {
        load_lds16(Ag + k0,             AsB);
        load_lds16(Ag + k0 + 16 * 1024, AsB + 512);
        load_lds16(Bg + k0,             BsB);
        load_lds16(Bg + k0 + 16 * 1024, BsB + 512);
        __syncthreads();
        short8 af[4], bfr[4];
        #pragma unroll
        for (int m = 0; m < 4; ++m)
            af[m] = *(const short8*)&As[wr * 64 + m * 16 + row16][g8 * 8];
        #pragma unroll
        for (int nn = 0; nn < 4; ++nn)
            bfr[nn] = *(const short8*)&Bs[wc * 64 + nn * 16 + row16][g8 * 8];
        #pragma unroll
        for (int m = 0; m < 4; ++m)
            #pragma unroll
            for (int nn = 0; nn < 4; ++nn)
                acc[m][nn] = MFMA16(af[m], bfr[nn], acc[m][nn]);
        __syncthreads();
    }

    #pragma unroll
    for (int m = 0; m < 4; ++m)
        #pragma unroll
        for (int nn = 0; nn < 4; ++nn) {
            int c = col0 + wc * 64 + nn * 16 + row16;
            #pragma unroll
            for (int reg = 0; reg < 4; ++reg) {
                int r = row0 + wr * 64 + m * 16 + g8 * 4 + reg;
                C[(size_t)r * D_MODELC + c] = acc[m][nn][reg];
            }
        }
}

// ---------------------------------------------------------------------------
// MFMA flash attention, j-steps strided across the block's 4 waves.
// Block = 16 q-rows x one (b,n). Per-wave online softmax; LDS merge at end.
// ---------------------------------------------------------------------------
__global__ __launch_bounds__(256, 4) void attn_mfma_kernel(
    const short* __restrict__ qw, const short* __restrict__ qr,
    const short* __restrict__ kb, const short* __restrict__ rkb,
    const short* __restrict__ vt, short* __restrict__ av)
{
    __shared__ float u_lds[4][16][84];   // bd scratch in-loop; scaled-O after
    __shared__ short p_lds[4][16][72];
    __shared__ float mlds[4][2][16];

    const int wave = threadIdx.x >> 6, lane = threadIdx.x & 63;
    const int row16 = lane & 15, g8 = lane >> 4;

    const int lin = blockIdx.y * 64 + blockIdx.x;       // 0..2047
    const int sw  = (lin & 7) * 256 + (lin >> 3);       // XCD-contiguous bn
    const int bn  = sw >> 6;
    const int i0  = (sw & 63) * 16;
    const int b = bn & 1, n = bn >> 1;

    short8 qwf[2], qrf[2];
    #pragma unroll
    for (int ks = 0; ks < 2; ++ks) {
        size_t off = ((size_t)(i0 + row16) * 2 + b) * D_MODELC + n * 64 + ks * 32 + g8 * 8;
        qwf[ks] = *(const short8*)(qw + off);
        qrf[ks] = *(const short8*)(qr + off);
    }

    f32x4 accO[4];
    #pragma unroll
    for (int dt = 0; dt < 4; ++dt) accO[dt] = (f32x4){0.f, 0.f, 0.f, 0.f};
    float m[4] = {-INFINITY, -INFINITY, -INFINITY, -INFINITY};
    float lsum[4] = {0.f, 0.f, 0.f, 0.f};

    const int T = (i0 + 15 + MEMLENC + 64) >> 6;        // total 64-key steps

    for (int s = wave; s < T; s += 4) {
        const int j0 = s * 64;

        // ---- AC = (q+rwb) @ K^T ----
        f32x4 ac[4];
        #pragma unroll
        for (int jt = 0; jt < 4; ++jt) {
            ac[jt] = (f32x4){0.f, 0.f, 0.f, 0.f};
            const short* kr = kb + ((size_t)(j0 + jt * 16 + row16) * 2 + b) * D_MODELC + n * 64 + g8 * 8;
            ac[jt] = MFMA16(qwf[0], *(const short8*)kr, ac[jt]);
            ac[jt] = MFMA16(qwf[1], *(const short8*)(kr + 32), ac[jt]);
        }

        // ---- BD over jr window [jrb, jrb+80) ----
        const int jrb = j0 - i0 + 1008;
        #pragma unroll
        for (int rt = 0; rt < 5; ++rt) {
            f32x4 bd = (f32x4){0.f, 0.f, 0.f, 0.f};
            int jr = jrb + rt * 16 + row16;
            if (jr > KLENC - 1) jr = KLENC - 1;          // masked region only
            const short* rr = rkb + (size_t)jr * D_MODELC + n * 64 + g8 * 8;
            bd = MFMA16(qrf[0], *(const short8*)rr, bd);
            bd = MFMA16(qrf[1], *(const short8*)(rr + 32), bd);
            #pragma unroll
            for (int e = 0; e < 4; ++e)
                u_lds[wave][g8 * 4 + e][rt * 16 + row16] = bd[e];
        }

        // ---- combine + mask + online softmax ----
        float S[4][4];
        #pragma unroll
        for (int reg = 0; reg < 4; ++reg) {
            const int i_loc = g8 * 4 + reg;
            const int ii = i0 + i_loc;
            #pragma unroll
            for (int jt = 0; jt < 4; ++jt) {
                const int j_loc = jt * 16 + row16;
                float sv = ac[jt][reg] + u_lds[wave][i_loc][j_loc - i_loc + 15];
                S[reg][jt] = ((j0 + j_loc) > (ii + MEMLENC)) ? -INFINITY : sv * SCALEC;
            }
        }
        float rm[4];
        #pragma unroll
        for (int reg = 0; reg < 4; ++reg)
            rm[reg] = fmaxf(fmaxf(S[reg][0], S[reg][1]), fmaxf(S[reg][2], S[reg][3]));
        #pragma unroll
        for (int off = 8; off >= 1; off >>= 1)
            #pragma unroll
            for (int reg = 0; reg < 4; ++reg)
                rm[reg] = fmaxf(rm[reg], __shfl_xor(rm[reg], off, 64));
        float sc[4];
        #pragma unroll
        for (int reg = 0; reg < 4; ++reg) {
            float mn = fmaxf(m[reg], rm[reg]);
            sc[reg] = __expf(m[reg] - mn);
            m[reg] = mn;
        }
        float P[4][4], rs[4];
        #pragma unroll
        for (int reg = 0; reg < 4; ++reg) {
            #pragma unroll
            for (int jt = 0; jt < 4; ++jt)
                P[reg][jt] = __expf(S[reg][jt] - m[reg]);
            rs[reg] = (P[reg][0] + P[reg][1]) + (P[reg][2] + P[reg][3]);
        }
        #pragma unroll
        for (int off = 8; off >= 1; off >>= 1)
            #pragma unroll
            for (int reg = 0; reg < 4; ++reg)
                rs[reg] += __shfl_xor(rs[reg], off, 64);
        #pragma unroll
        for (int reg = 0; reg < 4; ++reg)
            lsum[reg] = lsum[reg] * sc[reg] + rs[reg];
        #pragma unroll
        for (int dt = 0; dt < 4; ++dt)
            #pragma unroll
            for (int reg = 0; reg < 4; ++reg)
                accO[dt][reg] *= sc[reg];
        #pragma unroll
        for (int reg = 0; reg < 4; ++reg)
            #pragma unroll
            for (int jt = 0; jt < 4; ++jt)
                p_lds[wave][g8 * 4 + reg][jt * 16 + row16] = (short)f2bf(P[reg][jt]);

        // ---- PV: O += P @ V  (vt[b,n][d][j]) ----
        #pragma unroll
        for (int ks2 = 0; ks2 < 2; ++ks2) {
            short8 pf = *(const short8*)&p_lds[wave][row16][ks2 * 32 + g8 * 8];
            #pragma unroll
            for (int dt = 0; dt < 4; ++dt) {
                const short* vr = vt + ((size_t)(b * 16 + n) * 64 + dt * 16 + row16) * (size_t)KLENC
                                  + j0 + ks2 * 32 + g8 * 8;
                accO[dt] = MFMA16(pf, *(const short8*)vr, accO[dt]);
            }
        }
    }

    // ---- merge the 4 per-wave partials ----
    if (row16 == 0) {
        #pragma unroll
        for (int reg = 0; reg < 4; ++reg) {
            mlds[wave][0][g8 * 4 + reg] = m[reg];
            mlds[wave][1][g8 * 4 + reg] = lsum[reg];
        }
    }
    __syncthreads();
    float f[4];
    #pragma unroll
    for (int reg = 0; reg < 4; ++reg) {
        int rr = g8 * 4 + reg;
        float gm = fmaxf(fmaxf(mlds[0][0][rr], mlds[1][0][rr]),
                         fmaxf(mlds[2][0][rr], mlds[3][0][rr]));
        f[reg] = __expf(m[reg] - gm);
    }
    #pragma unroll
    for (int dt = 0; dt < 4; ++dt)
        #pragma unroll
        for (int reg = 0; reg < 4; ++reg)
            u_lds[wave][g8 * 4 + reg][dt * 16 + row16] = accO[dt][reg] * f[reg];
    __syncthreads();

    #pragma unroll
    for (int qq = 0; qq < 4; ++qq) {
        const int rr = wave * 4 + qq;
        float gm = fmaxf(fmaxf(mlds[0][0][rr], mlds[1][0][rr]),
                         fmaxf(mlds[2][0][rr], mlds[3][0][rr]));
        float gl = mlds[0][1][rr] * __expf(mlds[0][0][rr] - gm)
                 + mlds[1][1][rr] * __expf(mlds[1][0][rr] - gm)
                 + mlds[2][1][rr] * __expf(mlds[2][0][rr] - gm)
                 + mlds[3][1][rr] * __expf(mlds[3][0][rr] - gm);
        float ov = u_lds[0][rr][lane] + u_lds[1][rr][lane]
                 + u_lds[2][rr][lane] + u_lds[3][rr][lane];
        av[((size_t)(i0 + rr) * 2 + b) * D_MODELC + n * 64 + lane] = (short)f2bf(ov / gl);
    }
}

// ---------------------------------------------------------------------------
// Residual + bias + LayerNorm: x = w + ao0 + ao1 + bo
// ---------------------------------------------------------------------------
__global__ __launch_bounds__(256) void ln_kernel(
    const float* __restrict__ w, const float* __restrict__ ao0,
    const float* __restrict__ ao1, const float* __restrict__ bo,
    const float* __restrict__ g, const float* __restrict__ bb,
    float* __restrict__ out)
{
    __shared__ float red[2][4];
    const int row = blockIdx.x;
    const int lane = threadIdx.x & 63;
    const int wv = threadIdx.x >> 6;
    const size_t base = (size_t)row * D_MODELC;
    const int c = threadIdx.x * 4;

    float4 xw = *(const float4*)&w[base + c];
    float4 x0 = *(const float4*)&ao0[base + c];
    float4 x1 = *(const float4*)&ao1[base + c];
    float4 xb = *(const float4*)&bo[c];
    float x[4] = {xw.x + x0.x + x1.x + xb.x, xw.y + x0.y + x1.y + xb.y,
                  xw.z + x0.z + x1.z + xb.z, xw.w + x0.w + x1.w + xb.w};

    float sum = x[0] + x[1] + x[2] + x[3];
    float ssq = x[0]*x[0] + x[1]*x[1] + x[2]*x[2] + x[3]*x[3];
    #pragma unroll
    for (int off = 32; off > 0; off >>= 1) {
        sum += __shfl_xor(sum, off, 64);
        ssq += __shfl_xor(ssq, off, 64);
    }
    if (lane == 0) { red[0][wv] = sum; red[1][wv] = ssq; }
    __syncthreads();
    sum = red[0][0] + red[0][1] + red[0][2] + red[0][3];
    ssq = red[1][0] + red[1][1] + red[1][2] + red[1][3];

    const float mu = sum * (1.0f / D_MODELC);
    const float var = ssq * (1.0f / D_MODELC) - mu * mu;
    const float rstd = rsqrtf(var + LN_EPSC);

    float4 o;
    o.x = (x[0] - mu) * rstd * g[c] + bb[c];
    o.y = (x[1] - mu) * rstd * g[c+1] + bb[c+1];
    o.z = (x[2] - mu) * rstd * g[c+2] + bb[c+2];
    o.w = (x[3] - mu) * rstd * g[c+3] + bb[c+3];
    *(float4*)&out[base + c] = o;
}

// ---------------------------------------------------------------------------
extern "C" void kernel_launch(void* const* d_in, const int* in_sizes, int n_in,
                              void* d_out, int out_size, void* d_ws, size_t ws_size,
                              hipStream_t stream)
{
    const float* w    = (const float*)d_in[0];
    const float* r    = (const float*)d_in[1];
    const float* mems = (const float*)d_in[2];
    const float* rwb  = (const float*)d_in[3];
    const float* rrb  = (const float*)d_in[4];
    // d_in[5] = attn_mask — deterministic causal+mem pattern, handled analytically
    const float* Wq = (const float*)d_in[6];
    const float* bq = (const float*)d_in[7];
    const float* Wk = (const float*)d_in[8];
    const float* bk = (const float*)d_in[9];
    const float* Wv = (const float*)d_in[10];
    const float* bv = (const float*)d_in[11];
    const float* Wr = (const float*)d_in[12];
    const float* br = (const float*)d_in[13];
    const float* Wo = (const float*)d_in[14];
    const float* bo = (const float*)d_in[15];
    const float* ln_g = (const float*)d_in[16];
    const float* ln_b = (const float*)d_in[17];
    float* out = (float*)d_out;

    char* ws = (char*)d_ws;
    const size_t MB = 1ull << 20;
    short* cat_bf = (short*)(ws + 0 * MB);    // [4096][1024] (8 MB)
    short* r_bf   = (short*)(ws + 8 * MB);    // [2048][1024] (4 MB)
    short* Wq_t   = (short*)(ws + 12 * MB);
    short* Wk_t   = (short*)(ws + 14 * MB);
    short* Wv_t   = (short*)(ws + 16 * MB);
    short* Wr_t   = (short*)(ws + 18 * MB);
    short* Wo_t   = (short*)(ws + 20 * MB);
    short* qw_bf  = (short*)(ws + 22 * MB);   // [2048][1024]
    short* qr_bf  = (short*)(ws + 26 * MB);
    short* k_bf   = (short*)(ws + 30 * MB);   // [4096][1024] (8 MB)
    short* v_bf   = (short*)(ws + 38 * MB);   // [4096][1024] (8 MB)
    short* rk_bf  = (short*)(ws + 46 * MB);   // [2048][1024]
    short* vt     = (short*)(ws + 50 * MB);   // [2][16][64][2048] (8 MB)
    short* av_bf  = (short*)(ws + 58 * MB);   // [2048][1024]
    float* ao0    = (float*)v_bf;             // v_bf dead after vtrans
    float* ao1    = (float*)k_bf;             // k_bf dead after attn

    dim3 blk(256);

    // casts
    cast_cat_kernel<<<dim3(2048), blk, 0, stream>>>(mems, w, 2048 * 1024, cat_bf);
    cast_cat_kernel<<<dim3(1024), blk, 0, stream>>>(r, r, 1 << 30, r_bf);

    // fused weight transposes
    tcast5_kernel<<<dim3(16, 16, 5), blk, 0, stream>>>(
        Wq, Wk, Wv, Wr, Wo, Wq_t, Wk_t, Wv_t, Wr_t, Wo_t);

    // fused projections (K, V, Q->qw/qr, RK)
    proj_gemm_kernel<<<dim3(8, 96), blk, 0, stream>>>(
        cat_bf, r_bf, Wq_t, Wk_t, Wv_t, Wr_t,
        bq, bk, bv, br, rwb, rrb,
        qw_bf, qr_bf, k_bf, v_bf, rk_bf);

    // V transpose
    vtrans_kernel<<<dim3(32, 32), blk, 0, stream>>>(v_bf, vt);

    // attention
    attn_mfma_kernel<<<dim3(64, 32), blk, 0, stream>>>(
        qw_bf, qr_bf, k_bf, rk_bf, vt, av_bf);

    // output projection split-K (fp32 partials; bias in LN)
    wo_gemm_kernel<<<dim3(8, 16, 2), blk, 0, stream>>>(av_bf, Wo_t, ao0, ao1);

    // LN(w + ao0 + ao1 + bo)
    ln_kernel<<<dim3(2048), blk, 0, stream>>>(w, ao0, ao1, bo, ln_g, ln_b, out);
}

// Round 4
// 176.928 us; speedup vs baseline: 24.0674x; 1.4620x over previous
//
#include <hip/hip_runtime.h>
#include <math.h>

#define N_HEADC 16
#define D_MODELC 1024
#define D_HEADC 64
#define QLENC 1024
#define BSZC 2
#define MEMLENC 1024
#define KLENC 2048
#define SCALEC 0.125f
#define LN_EPSC 1e-5f
#define RINGC 192

typedef __attribute__((ext_vector_type(8))) short short8;
typedef __attribute__((ext_vector_type(4))) float f32x4;

#define MFMA16(a, b, c) __builtin_amdgcn_mfma_f32_16x16x32_bf16((a), (b), (c), 0, 0, 0)

__device__ inline unsigned short f2bf(float x) {
    union { float f; unsigned int u; } c; c.f = x;
    unsigned int r = c.u + 0x7FFFu + ((c.u >> 16) & 1u);
    return (unsigned short)(r >> 16);
}
__device__ inline float bf2f(short s) {
    union { unsigned int u; float f; } c; c.u = ((unsigned int)(unsigned short)s) << 16;
    return c.f;
}

// async global->LDS, 16B per lane; lds dest = wave-uniform base + lane*16
__device__ __forceinline__ void load_lds16(const short* g, short* l) {
    __builtin_amdgcn_global_load_lds(
        (const __attribute__((address_space(1))) void*)g,
        (__attribute__((address_space(3))) void*)l,
        16, 0, 0);
}

// ---------------------------------------------------------------------------
// fp32 -> bf16 cast with optional split source (for cat = [mems; w])
// ---------------------------------------------------------------------------
__global__ __launch_bounds__(256) void cast_cat_kernel(
    const float* __restrict__ s0, const float* __restrict__ s1, int splitElems,
    short* __restrict__ dst)
{
    int idx = (blockIdx.x * 256 + threadIdx.x) * 8;
    const float* src = (idx < splitElems) ? (s0 + idx) : (s1 + (idx - splitElems));
    short8 o;
    #pragma unroll
    for (int e = 0; e < 8; ++e) o[e] = (short)f2bf(src[e]);
    *(short8*)(dst + idx) = o;
}

// ---------------------------------------------------------------------------
// 5 weight transposes fused: W fp32 [1024][1024] -> Wt bf16 [n][k]
// ---------------------------------------------------------------------------
__global__ __launch_bounds__(256) void tcast5_kernel(
    const float* __restrict__ W0, const float* __restrict__ W1,
    const float* __restrict__ W2, const float* __restrict__ W3,
    const float* __restrict__ W4,
    short* __restrict__ D0, short* __restrict__ D1, short* __restrict__ D2,
    short* __restrict__ D3, short* __restrict__ D4)
{
    __shared__ short tile[64][72];
    const float* W; short* D;
    switch (blockIdx.z) {
        case 0: W = W0; D = D0; break;
        case 1: W = W1; D = D1; break;
        case 2: W = W2; D = D2; break;
        case 3: W = W3; D = D3; break;
        default: W = W4; D = D4; break;
    }
    const int t = threadIdx.x;
    const int n0 = blockIdx.x * 64, k0 = blockIdx.y * 64;
    #pragma unroll
    for (int it = 0; it < 2; ++it) {
        int idx = t + it * 256;
        int kl = idx >> 3, c8 = idx & 7;
        const float* src = W + (size_t)(k0 + kl) * D_MODELC + n0 + c8 * 8;
        short8 s;
        #pragma unroll
        for (int e = 0; e < 8; ++e) s[e] = (short)f2bf(src[e]);
        *(short8*)&tile[kl][c8 * 8] = s;
    }
    __syncthreads();
    #pragma unroll
    for (int it = 0; it < 2; ++it) {
        int idx = t + it * 256;
        int nl = idx >> 3, c8 = idx & 7;
        short8 s;
        #pragma unroll
        for (int e = 0; e < 8; ++e) s[e] = tile[c8 * 8 + e][nl];
        *(short8*)(D + (size_t)(n0 + nl) * D_MODELC + k0 + c8 * 8) = s;
    }
}

// ---------------------------------------------------------------------------
// V transpose: v_bf [4096][1024] (row=j*2+b, col=n*64+d) -> vt [b][n][d=64][j=2048]
// ---------------------------------------------------------------------------
__global__ __launch_bounds__(256) void vtrans_kernel(
    const short* __restrict__ v_bf, short* __restrict__ vt)
{
    __shared__ short tile[64][72];
    const int t = threadIdx.x;
    const int j0 = blockIdx.x * 64;
    const int bn = blockIdx.y;
    const int b = bn & 1, n = bn >> 1;
    #pragma unroll
    for (int it = 0; it < 2; ++it) {
        int idx = t + it * 256;
        int jl = idx >> 3, c8 = idx & 7;
        short8 s = *(const short8*)(v_bf + ((size_t)(j0 + jl) * 2 + b) * D_MODELC + n * 64 + c8 * 8);
        *(short8*)&tile[jl][c8 * 8] = s;
    }
    __syncthreads();
    #pragma unroll
    for (int it = 0; it < 2; ++it) {
        int idx = t + it * 256;
        int dl = idx >> 3, c8 = idx & 7;
        short8 s;
        #pragma unroll
        for (int e = 0; e < 8; ++e) s[e] = tile[c8 * 8 + e][dl];
        *(short8*)(vt + ((size_t)(b * 16 + n) * 64 + dl) * (size_t)KLENC + j0 + c8 * 8) = s;
    }
}

// ---------------------------------------------------------------------------
// Fused projection GEMMs (K, V, Q, RK) via global_load_lds, 128x128 tile, BK=32.
// ---------------------------------------------------------------------------
__global__ __launch_bounds__(256, 3) void proj_gemm_kernel(
    const short* __restrict__ cat, const short* __restrict__ rin,
    const short* __restrict__ WqT, const short* __restrict__ WkT,
    const short* __restrict__ WvT, const short* __restrict__ WrT,
    const float* __restrict__ bq, const float* __restrict__ bk,
    const float* __restrict__ bv, const float* __restrict__ br,
    const float* __restrict__ rwb, const float* __restrict__ rrb,
    short* __restrict__ qw, short* __restrict__ qr,
    short* __restrict__ kb, short* __restrict__ vb, short* __restrict__ rk)
{
    __shared__ short As[128][32];
    __shared__ short Bs[128][32];

    const int lin = blockIdx.y * 8 + blockIdx.x;        // 0..767
    const int sw  = (lin & 7) * 96 + (lin >> 3);        // XCD-contiguous
    const int bx  = sw & 7;
    const int by  = sw >> 3;

    const short* A; const short* Bt; const float* bias; int yt, mode;
    if (by < 32)      { A = cat;                         Bt = WkT; bias = bk; yt = by;      mode = 0; }
    else if (by < 64) { A = cat;                         Bt = WvT; bias = bv; yt = by - 32; mode = 1; }
    else if (by < 80) { A = cat + (size_t)2048 * 1024;   Bt = WqT; bias = bq; yt = by - 64; mode = 2; }
    else              { A = rin;                         Bt = WrT; bias = br; yt = by - 80; mode = 3; }

    const int row0 = yt * 128, col0 = bx * 128;
    const int t = threadIdx.x;
    const int lane = t & 63, wid = t >> 6;
    const int row16 = lane & 15, g8 = lane >> 4;
    const int wr = wid >> 1, wc = wid & 1;

    f32x4 acc[4][4];
    #pragma unroll
    for (int m = 0; m < 4; ++m)
        #pragma unroll
        for (int nn = 0; nn < 4; ++nn)
            acc[m][nn] = (f32x4){0.f, 0.f, 0.f, 0.f};

    short* AsB = &As[0][0] + wid * 1024;
    short* BsB = &Bs[0][0] + wid * 1024;
    const short* Ag = A  + (size_t)(row0 + wid * 32 + (lane >> 2)) * D_MODELC + (lane & 3) * 8;
    const short* Bg = Bt + (size_t)(col0 + wid * 32 + (lane >> 2)) * D_MODELC + (lane & 3) * 8;

    for (int k0 = 0; k0 < D_MODELC; k0 += 32) {
        load_lds16(Ag + k0,              AsB);
        load_lds16(Ag + k0 + 16 * 1024,  AsB + 512);
        load_lds16(Bg + k0,              BsB);
        load_lds16(Bg + k0 + 16 * 1024,  BsB + 512);
        __syncthreads();
        short8 af[4], bfr[4];
        #pragma unroll
        for (int m = 0; m < 4; ++m)
            af[m] = *(const short8*)&As[wr * 64 + m * 16 + row16][g8 * 8];
        #pragma unroll
        for (int nn = 0; nn < 4; ++nn)
            bfr[nn] = *(const short8*)&Bs[wc * 64 + nn * 16 + row16][g8 * 8];
        #pragma unroll
        for (int m = 0; m < 4; ++m)
            #pragma unroll
            for (int nn = 0; nn < 4; ++nn)
                acc[m][nn] = MFMA16(af[m], bfr[nn], acc[m][nn]);
        __syncthreads();
    }

    float bvv[4], w1[4], w2[4];
    #pragma unroll
    for (int nn = 0; nn < 4; ++nn) {
        int c = col0 + wc * 64 + nn * 16 + row16;
        bvv[nn] = bias[c];
        w1[nn] = rwb[c];
        w2[nn] = rrb[c];
    }
    if (mode == 2) {
        #pragma unroll
        for (int m = 0; m < 4; ++m)
            #pragma unroll
            for (int nn = 0; nn < 4; ++nn) {
                int c = col0 + wc * 64 + nn * 16 + row16;
                #pragma unroll
                for (int reg = 0; reg < 4; ++reg) {
                    int r = row0 + wr * 64 + m * 16 + g8 * 4 + reg;
                    float v = acc[m][nn][reg] + bvv[nn];
                    qw[(size_t)r * D_MODELC + c] = (short)f2bf(v + w1[nn]);
                    qr[(size_t)r * D_MODELC + c] = (short)f2bf(v + w2[nn]);
                }
            }
    } else {
        short* C = (mode == 0) ? kb : (mode == 1) ? vb : rk;
        #pragma unroll
        for (int m = 0; m < 4; ++m)
            #pragma unroll
            for (int nn = 0; nn < 4; ++nn) {
                int c = col0 + wc * 64 + nn * 16 + row16;
                #pragma unroll
                for (int reg = 0; reg < 4; ++reg) {
                    int r = row0 + wr * 64 + m * 16 + g8 * 4 + reg;
                    C[(size_t)r * D_MODELC + c] = (short)f2bf(acc[m][nn][reg] + bvv[nn]);
                }
            }
    }
}

// ---------------------------------------------------------------------------
// Wo GEMM, split-K=2: fp32 partials (bias added in LN)
// ---------------------------------------------------------------------------
__global__ __launch_bounds__(256, 3) void wo_gemm_kernel(
    const short* __restrict__ A, const short* __restrict__ Bt,
    float* __restrict__ out0, float* __restrict__ out1)
{
    __shared__ short As[128][32];
    __shared__ short Bs[128][32];
    const int kz = blockIdx.z;
    float* C = kz ? out1 : out0;
    const int row0 = blockIdx.y * 128, col0 = blockIdx.x * 128;
    const int t = threadIdx.x;
    const int lane = t & 63, wid = t >> 6;
    const int row16 = lane & 15, g8 = lane >> 4;
    const int wr = wid >> 1, wc = wid & 1;

    f32x4 acc[4][4];
    #pragma unroll
    for (int m = 0; m < 4; ++m)
        #pragma unroll
        for (int nn = 0; nn < 4; ++nn)
            acc[m][nn] = (f32x4){0.f, 0.f, 0.f, 0.f};

    short* AsB = &As[0][0] + wid * 1024;
    short* BsB = &Bs[0][0] + wid * 1024;
    const short* Ag = A  + (size_t)(row0 + wid * 32 + (lane >> 2)) * D_MODELC + (lane & 3) * 8;
    const short* Bg = Bt + (size_t)(col0 + wid * 32 + (lane >> 2)) * D_MODELC + (lane & 3) * 8;

    const int kbase = kz * 512;
    for (int k0 = kbase; k0 < kbase + 512; k0 += 32) {
        load_lds16(Ag + k0,             AsB);
        load_lds16(Ag + k0 + 16 * 1024, AsB + 512);
        load_lds16(Bg + k0,             BsB);
        load_lds16(Bg + k0 + 16 * 1024, BsB + 512);
        __syncthreads();
        short8 af[4], bfr[4];
        #pragma unroll
        for (int m = 0; m < 4; ++m)
            af[m] = *(const short8*)&As[wr * 64 + m * 16 + row16][g8 * 8];
        #pragma unroll
        for (int nn = 0; nn < 4; ++nn)
            bfr[nn] = *(const short8*)&Bs[wc * 64 + nn * 16 + row16][g8 * 8];
        #pragma unroll
        for (int m = 0; m < 4; ++m)
            #pragma unroll
            for (int nn = 0; nn < 4; ++nn)
                acc[m][nn] = MFMA16(af[m], bfr[nn], acc[m][nn]);
        __syncthreads();
    }

    #pragma unroll
    for (int m = 0; m < 4; ++m)
        #pragma unroll
        for (int nn = 0; nn < 4; ++nn) {
            int c = col0 + wc * 64 + nn * 16 + row16;
            #pragma unroll
            for (int reg = 0; reg < 4; ++reg) {
                int r = row0 + wr * 64 + m * 16 + g8 * 4 + reg;
                C[(size_t)r * D_MODELC + c] = acc[m][nn][reg];
            }
        }
}

// ---------------------------------------------------------------------------
// LDS-staged MFMA flash attention with Transformer-XL relative shift.
// Block = 64 q-rows (4 waves i-split, 16 rows each) x one (b,n).
// Shared j-loop: K tile double-buffered, V tile single-buffered, rk in a
// 192-row ring (window slides +64/step). All staging via global_load_lds
// with XOR-swizzled global source; frag reads apply the same swizzle.
// ---------------------------------------------------------------------------
__global__ __launch_bounds__(256, 2) void attn_mfma_kernel(
    const short* __restrict__ qw, const short* __restrict__ qr,
    const short* __restrict__ kb, const short* __restrict__ rkb,
    const short* __restrict__ vt, short* __restrict__ av)
{
    __shared__ short Kl[2][64][64];      // 16 KB (dbuf)
    __shared__ short Vl[64][64];         // 8 KB  ([d][j])
    __shared__ short Rl[RINGC][64];      // 24 KB (rk ring, row = jr % 192)
    __shared__ short pw[4][16][88];      // 11 KB (per-wave: BD scratch then P)

    const int wave = threadIdx.x >> 6, lane = threadIdx.x & 63;
    const int row16 = lane & 15, g8 = lane >> 4;
    const int srow = lane >> 3, chk = lane & 7;
    const int swz = srow & 7;            // staging source-chunk xor

    const int lin = blockIdx.y * 16 + blockIdx.x;   // 0..511
    const int sw  = (lin & 7) * 64 + (lin >> 3);    // XCD-contiguous
    const int bn  = sw >> 4;
    const int ic  = sw & 15;
    const int b = bn & 1, n = bn >> 1;
    const int i0 = ic * 64;
    const int i0w = i0 + wave * 16;

    // Q fragments (row = i0w+row16, k = ks*32 + g8*8 + e)
    short8 qwf[2], qrf[2];
    #pragma unroll
    for (int ks = 0; ks < 2; ++ks) {
        size_t off = ((size_t)(i0w + row16) * 2 + b) * D_MODELC + n * 64 + ks * 32 + g8 * 8;
        qwf[ks] = *(const short8*)(qw + off);
        qrf[ks] = *(const short8*)(qr + off);
    }

    // ---- prologue: stage K(step0) and rk window(0) = [960-i0, 1088-i0) ----
    #pragma unroll
    for (int t = 0; t < 2; ++t) {
        int rr = wave * 16 + t * 8;
        int j  = rr + srow;                       // j0 = 0
        int cs = chk ^ swz;                       // j&7 == srow
        load_lds16(kb + ((size_t)j * 2 + b) * D_MODELC + n * 64 + cs * 8, &Kl[0][rr][0]);
    }
    {
        const int p0 = 960 - i0;                  // multiple of 8 (>=0)
        #pragma unroll
        for (int t = 0; t < 4; ++t) {
            int jrb_ = p0 + wave * 32 + t * 8;
            int slotb = jrb_ % RINGC;
            int jr = jrb_ + srow;
            int jc = jr < KLENC ? jr : KLENC - 1;
            int cs = chk ^ swz;                   // jr&7 == srow
            load_lds16(rkb + (size_t)jc * D_MODELC + n * 64 + cs * 8, &Rl[slotb][0]);
        }
    }

    f32x4 accO[4];
    #pragma unroll
    for (int dt = 0; dt < 4; ++dt) accO[dt] = (f32x4){0.f, 0.f, 0.f, 0.f};
    float m[4] = {-INFINITY, -INFINITY, -INFINITY, -INFINITY};
    float lsum[4] = {0.f, 0.f, 0.f, 0.f};

    const int T = (i0 + 63 + MEMLENC + 64) >> 6;  // block-uniform step count
    const int xr7 = (row16 & 7);

    __syncthreads();

    for (int s = 0; s < T; ++s) {
        const int j0 = s * 64;
        const int cur = s & 1, nxt = cur ^ 1;

        // ---------- phase A: issue async staging (lands by the barrier) ----------
        #pragma unroll
        for (int t = 0; t < 2; ++t) {             // K(s+1)
            int rr = wave * 16 + t * 8;
            int j  = j0 + 64 + rr + srow;
            if (j > KLENC - 1) j = KLENC - 1;
            int cs = chk ^ swz;
            load_lds16(kb + ((size_t)j * 2 + b) * D_MODELC + n * 64 + cs * 8, &Kl[nxt][rr][0]);
        }
        {
            const int nb = j0 + 1088 - i0;        // new rk rows for window(s+1)
            #pragma unroll
            for (int t = 0; t < 2; ++t) {
                int jrb_ = nb + wave * 16 + t * 8;
                int slotb = jrb_ % RINGC;
                int jr = jrb_ + srow;
                int jc = jr < KLENC ? jr : KLENC - 1;
                int cs = chk ^ swz;
                load_lds16(rkb + (size_t)jc * D_MODELC + n * 64 + cs * 8, &Rl[slotb][0]);
            }
        }
        #pragma unroll
        for (int t = 0; t < 2; ++t) {             // V(s), d-major
            int rr = wave * 16 + t * 8;
            int cs = chk ^ swz;
            load_lds16(vt + ((size_t)((b * 16 + n) * 64 + rr + srow)) * KLENC + j0 + cs * 8,
                       &Vl[rr][0]);
        }

        // ---------- AC = (q+rwb) @ K^T from Kl[cur] ----------
        f32x4 ac[4];
        #pragma unroll
        for (int jt = 0; jt < 4; ++jt) {
            ac[jt] = (f32x4){0.f, 0.f, 0.f, 0.f};
            const short* kr = &Kl[cur][jt * 16 + row16][0];
            ac[jt] = MFMA16(qwf[0], *(const short8*)(kr + ((g8 ^ xr7) * 8)), ac[jt]);
            ac[jt] = MFMA16(qwf[1], *(const short8*)(kr + (((4 + g8) ^ xr7) * 8)), ac[jt]);
        }

        // ---------- BD over jr window [jrb_w, jrb_w+80) from ring ----------
        const int jrb_w = j0 - i0w + 1008;        // >= 0, multiple of 8... (mod-8 = 0)
        const int sb = jrb_w % RINGC;
        #pragma unroll
        for (int rt = 0; rt < 5; ++rt) {
            int sl = sb + rt * 16 + row16;
            if (sl >= RINGC) sl -= RINGC;
            const short* rr = &Rl[sl][0];
            f32x4 bd = (f32x4){0.f, 0.f, 0.f, 0.f};
            bd = MFMA16(qrf[0], *(const short8*)(rr + ((g8 ^ xr7) * 8)), bd);
            bd = MFMA16(qrf[1], *(const short8*)(rr + (((4 + g8) ^ xr7) * 8)), bd);
            #pragma unroll
            for (int e = 0; e < 4; ++e)
                pw[wave][g8 * 4 + e][rt * 16 + row16] = (short)f2bf(bd[e]);
        }

        // ---------- combine + mask + online softmax ----------
        float S[4][4];
        #pragma unroll
        for (int reg = 0; reg < 4; ++reg) {
            const int i_loc = g8 * 4 + reg;
            const int ii = i0w + i_loc;
            #pragma unroll
            for (int jt = 0; jt < 4; ++jt) {
                const int j_loc = jt * 16 + row16;
                float sv = ac[jt][reg] + bf2f(pw[wave][i_loc][j_loc - i_loc + 15]);
                S[reg][jt] = ((j0 + j_loc) > (ii + MEMLENC)) ? -INFINITY : sv * SCALEC;
            }
        }
        float rm[4];
        #pragma unroll
        for (int reg = 0; reg < 4; ++reg)
            rm[reg] = fmaxf(fmaxf(S[reg][0], S[reg][1]), fmaxf(S[reg][2], S[reg][3]));
        #pragma unroll
        for (int off = 8; off >= 1; off >>= 1)
            #pragma unroll
            for (int reg = 0; reg < 4; ++reg)
                rm[reg] = fmaxf(rm[reg], __shfl_xor(rm[reg], off, 64));
        float sc[4];
        #pragma unroll
        for (int reg = 0; reg < 4; ++reg) {
            float mn = fmaxf(m[reg], rm[reg]);
            sc[reg] = __expf(m[reg] - mn);
            m[reg] = mn;
        }
        float P[4][4], rs[4];
        #pragma unroll
        for (int reg = 0; reg < 4; ++reg) {
            #pragma unroll
            for (int jt = 0; jt < 4; ++jt)
                P[reg][jt] = __expf(S[reg][jt] - m[reg]);
            rs[reg] = (P[reg][0] + P[reg][1]) + (P[reg][2] + P[reg][3]);
        }
        #pragma unroll
        for (int off = 8; off >= 1; off >>= 1)
            #pragma unroll
            for (int reg = 0; reg < 4; ++reg)
                rs[reg] += __shfl_xor(rs[reg], off, 64);
        #pragma unroll
        for (int reg = 0; reg < 4; ++reg)
            lsum[reg] = lsum[reg] * sc[reg] + rs[reg];
        #pragma unroll
        for (int dt = 0; dt < 4; ++dt)
            #pragma unroll
            for (int reg = 0; reg < 4; ++reg)
                accO[dt][reg] *= sc[reg];
        // P -> pw (cols 0..63; BD cols already consumed, same-wave DS order)
        #pragma unroll
        for (int reg = 0; reg < 4; ++reg)
            #pragma unroll
            for (int jt = 0; jt < 4; ++jt)
                pw[wave][g8 * 4 + reg][jt * 16 + row16] = (short)f2bf(P[reg][jt]);

        __syncthreads();   // drains staging; Vl/Kl[nxt]/Rl-new now valid

        // ---------- PV: O += P @ V from Vl ----------
        #pragma unroll
        for (int ks2 = 0; ks2 < 2; ++ks2) {
            short8 pf = *(const short8*)&pw[wave][row16][ks2 * 32 + g8 * 8];
            #pragma unroll
            for (int dt = 0; dt < 4; ++dt) {
                const short* vp = &Vl[dt * 16 + row16][(((ks2 * 4 + g8) ^ xr7) * 8)];
                accO[dt] = MFMA16(pf, *(const short8*)vp, accO[dt]);
            }
        }

        __syncthreads();   // protect Vl (restaged next phase A)
    }

    // ---- epilogue: each wave owns its 16 rows; no merge ----
    #pragma unroll
    for (int dt = 0; dt < 4; ++dt)
        #pragma unroll
        for (int reg = 0; reg < 4; ++reg) {
            size_t o = ((size_t)(i0w + g8 * 4 + reg) * 2 + b) * D_MODELC + n * 64 + dt * 16 + row16;
            av[o] = (short)f2bf(accO[dt][reg] / lsum[reg]);
        }
}

// ---------------------------------------------------------------------------
// Residual + bias + LayerNorm: x = w + ao0 + ao1 + bo
// ---------------------------------------------------------------------------
__global__ __launch_bounds__(256) void ln_kernel(
    const float* __restrict__ w, const float* __restrict__ ao0,
    const float* __restrict__ ao1, const float* __restrict__ bo,
    const float* __restrict__ g, const float* __restrict__ bb,
    float* __restrict__ out)
{
    __shared__ float red[2][4];
    const int row = blockIdx.x;
    const int lane = threadIdx.x & 63;
    const int wv = threadIdx.x >> 6;
    const size_t base = (size_t)row * D_MODELC;
    const int c = threadIdx.x * 4;

    float4 xw = *(const float4*)&w[base + c];
    float4 x0 = *(const float4*)&ao0[base + c];
    float4 x1 = *(const float4*)&ao1[base + c];
    float4 xb = *(const float4*)&bo[c];
    float x[4] = {xw.x + x0.x + x1.x + xb.x, xw.y + x0.y + x1.y + xb.y,
                  xw.z + x0.z + x1.z + xb.z, xw.w + x0.w + x1.w + xb.w};

    float sum = x[0] + x[1] + x[2] + x[3];
    float ssq = x[0]*x[0] + x[1]*x[1] + x[2]*x[2] + x[3]*x[3];
    #pragma unroll
    for (int off = 32; off > 0; off >>= 1) {
        sum += __shfl_xor(sum, off, 64);
        ssq += __shfl_xor(ssq, off, 64);
    }
    if (lane == 0) { red[0][wv] = sum; red[1][wv] = ssq; }
    __syncthreads();
    sum = red[0][0] + red[0][1] + red[0][2] + red[0][3];
    ssq = red[1][0] + red[1][1] + red[1][2] + red[1][3];

    const float mu = sum * (1.0f / D_MODELC);
    const float var = ssq * (1.0f / D_MODELC) - mu * mu;
    const float rstd = rsqrtf(var + LN_EPSC);

    float4 o;
    o.x = (x[0] - mu) * rstd * g[c] + bb[c];
    o.y = (x[1] - mu) * rstd * g[c+1] + bb[c+1];
    o.z = (x[2] - mu) * rstd * g[c+2] + bb[c+2];
    o.w = (x[3] - mu) * rstd * g[c+3] + bb[c+3];
    *(float4*)&out[base + c] = o;
}

// ---------------------------------------------------------------------------
extern "C" void kernel_launch(void* const* d_in, const int* in_sizes, int n_in,
                              void* d_out, int out_size, void* d_ws, size_t ws_size,
                              hipStream_t stream)
{
    const float* w    = (const float*)d_in[0];
    const float* r    = (const float*)d_in[1];
    const float* mems = (const float*)d_in[2];
    const float* rwb  = (const float*)d_in[3];
    const float* rrb  = (const float*)d_in[4];
    // d_in[5] = attn_mask — deterministic causal+mem pattern, handled analytically
    const float* Wq = (const float*)d_in[6];
    const float* bq = (const float*)d_in[7];
    const float* Wk = (const float*)d_in[8];
    const float* bk = (const float*)d_in[9];
    const float* Wv = (const float*)d_in[10];
    const float* bv = (const float*)d_in[11];
    const float* Wr = (const float*)d_in[12];
    const float* br = (const float*)d_in[13];
    const float* Wo = (const float*)d_in[14];
    const float* bo = (const float*)d_in[15];
    const float* ln_g = (const float*)d_in[16];
    const float* ln_b = (const float*)d_in[17];
    float* out = (float*)d_out;

    char* ws = (char*)d_ws;
    const size_t MB = 1ull << 20;
    short* cat_bf = (short*)(ws + 0 * MB);    // [4096][1024] (8 MB)
    short* r_bf   = (short*)(ws + 8 * MB);    // [2048][1024] (4 MB)
    short* Wq_t   = (short*)(ws + 12 * MB);
    short* Wk_t   = (short*)(ws + 14 * MB);
    short* Wv_t   = (short*)(ws + 16 * MB);
    short* Wr_t   = (short*)(ws + 18 * MB);
    short* Wo_t   = (short*)(ws + 20 * MB);
    short* qw_bf  = (short*)(ws + 22 * MB);   // [2048][1024]
    short* qr_bf  = (short*)(ws + 26 * MB);
    short* k_bf   = (short*)(ws + 30 * MB);   // [4096][1024] (8 MB)
    short* v_bf   = (short*)(ws + 38 * MB);   // [4096][1024] (8 MB)
    short* rk_bf  = (short*)(ws + 46 * MB);   // [2048][1024]
    short* vt     = (short*)(ws + 50 * MB);   // [2][16][64][2048] (8 MB)
    short* av_bf  = (short*)(ws + 58 * MB);   // [2048][1024]
    float* ao0    = (float*)v_bf;             // v_bf dead after vtrans
    float* ao1    = (float*)k_bf;             // k_bf dead after attn

    dim3 blk(256);

    // casts
    cast_cat_kernel<<<dim3(2048), blk, 0, stream>>>(mems, w, 2048 * 1024, cat_bf);
    cast_cat_kernel<<<dim3(1024), blk, 0, stream>>>(r, r, 1 << 30, r_bf);

    // fused weight transposes
    tcast5_kernel<<<dim3(16, 16, 5), blk, 0, stream>>>(
        Wq, Wk, Wv, Wr, Wo, Wq_t, Wk_t, Wv_t, Wr_t, Wo_t);

    // fused projections (K, V, Q->qw/qr, RK)
    proj_gemm_kernel<<<dim3(8, 96), blk, 0, stream>>>(
        cat_bf, r_bf, Wq_t, Wk_t, Wv_t, Wr_t,
        bq, bk, bv, br, rwb, rrb,
        qw_bf, qr_bf, k_bf, v_bf, rk_bf);

    // V transpose
    vtrans_kernel<<<dim3(32, 32), blk, 0, stream>>>(v_bf, vt);

    // attention (LDS-staged): grid 512 = 16 i-chunks x 32 bn
    attn_mfma_kernel<<<dim3(16, 32), blk, 0, stream>>>(
        qw_bf, qr_bf, k_bf, rk_bf, vt, av_bf);

    // output projection split-K (fp32 partials; bias in LN)
    wo_gemm_kernel<<<dim3(8, 16, 2), blk, 0, stream>>>(av_bf, Wo_t, ao0, ao1);

    // LN(w + ao0 + ao1 + bo)
    ln_kernel<<<dim3(2048), blk, 0, stream>>>(w, ao0, ao1, bo, ln_g, ln_b, out);
}

// Round 6
// 159.774 us; speedup vs baseline: 26.6513x; 1.1074x over previous
//
#include <hip/hip_runtime.h>
#include <math.h>

#define N_HEADC 16
#define D_MODELC 1024
#define D_HEADC 64
#define QLENC 1024
#define BSZC 2
#define MEMLENC 1024
#define KLENC 2048
#define SCALEC 0.125f
#define SL2C 0.18033688011112042f   // SCALE * log2(e)
#define LN_EPSC 1e-5f
#define RINGC 192

typedef __attribute__((ext_vector_type(8))) short short8;
typedef __attribute__((ext_vector_type(4))) float f32x4;

#define MFMA16(a, b, c) __builtin_amdgcn_mfma_f32_16x16x32_bf16((a), (b), (c), 0, 0, 0)

__device__ inline unsigned short f2bf(float x) {
    union { float f; unsigned int u; } c; c.f = x;
    unsigned int r = c.u + 0x7FFFu + ((c.u >> 16) & 1u);
    return (unsigned short)(r >> 16);
}
__device__ inline float bf2f(short s) {
    union { unsigned int u; float f; } c; c.u = ((unsigned int)(unsigned short)s) << 16;
    return c.f;
}

// async global->LDS, 16B per lane; lds dest = wave-uniform base + lane*16
__device__ __forceinline__ void load_lds16(const short* g, short* l) {
    __builtin_amdgcn_global_load_lds(
        (const __attribute__((address_space(1))) void*)g,
        (__attribute__((address_space(3))) void*)l,
        16, 0, 0);
}

// ---------------------------------------------------------------------------
// fp32 -> bf16 cast with optional split source (for cat = [mems; w])
// ---------------------------------------------------------------------------
__global__ __launch_bounds__(256) void cast_cat_kernel(
    const float* __restrict__ s0, const float* __restrict__ s1, int splitElems,
    short* __restrict__ dst)
{
    int idx = (blockIdx.x * 256 + threadIdx.x) * 8;
    const float* src = (idx < splitElems) ? (s0 + idx) : (s1 + (idx - splitElems));
    short8 o;
    #pragma unroll
    for (int e = 0; e < 8; ++e) o[e] = (short)f2bf(src[e]);
    *(short8*)(dst + idx) = o;
}

// ---------------------------------------------------------------------------
// 5 weight transposes fused: W fp32 [1024][1024] -> Wt bf16 [n][k]
// ---------------------------------------------------------------------------
__global__ __launch_bounds__(256) void tcast5_kernel(
    const float* __restrict__ W0, const float* __restrict__ W1,
    const float* __restrict__ W2, const float* __restrict__ W3,
    const float* __restrict__ W4,
    short* __restrict__ D0, short* __restrict__ D1, short* __restrict__ D2,
    short* __restrict__ D3, short* __restrict__ D4)
{
    __shared__ short tile[64][72];
    const float* W; short* D;
    switch (blockIdx.z) {
        case 0: W = W0; D = D0; break;
        case 1: W = W1; D = D1; break;
        case 2: W = W2; D = D2; break;
        case 3: W = W3; D = D3; break;
        default: W = W4; D = D4; break;
    }
    const int t = threadIdx.x;
    const int n0 = blockIdx.x * 64, k0 = blockIdx.y * 64;
    #pragma unroll
    for (int it = 0; it < 2; ++it) {
        int idx = t + it * 256;
        int kl = idx >> 3, c8 = idx & 7;
        const float* src = W + (size_t)(k0 + kl) * D_MODELC + n0 + c8 * 8;
        short8 s;
        #pragma unroll
        for (int e = 0; e < 8; ++e) s[e] = (short)f2bf(src[e]);
        *(short8*)&tile[kl][c8 * 8] = s;
    }
    __syncthreads();
    #pragma unroll
    for (int it = 0; it < 2; ++it) {
        int idx = t + it * 256;
        int nl = idx >> 3, c8 = idx & 7;
        short8 s;
        #pragma unroll
        for (int e = 0; e < 8; ++e) s[e] = tile[c8 * 8 + e][nl];
        *(short8*)(D + (size_t)(n0 + nl) * D_MODELC + k0 + c8 * 8) = s;
    }
}

// ---------------------------------------------------------------------------
// V transpose: v_bf [4096][1024] (row=j*2+b, col=n*64+d) -> vt [b][n][d=64][j=2048]
// ---------------------------------------------------------------------------
__global__ __launch_bounds__(256) void vtrans_kernel(
    const short* __restrict__ v_bf, short* __restrict__ vt)
{
    __shared__ short tile[64][72];
    const int t = threadIdx.x;
    const int j0 = blockIdx.x * 64;
    const int bn = blockIdx.y;
    const int b = bn & 1, n = bn >> 1;
    #pragma unroll
    for (int it = 0; it < 2; ++it) {
        int idx = t + it * 256;
        int jl = idx >> 3, c8 = idx & 7;
        short8 s = *(const short8*)(v_bf + ((size_t)(j0 + jl) * 2 + b) * D_MODELC + n * 64 + c8 * 8);
        *(short8*)&tile[jl][c8 * 8] = s;
    }
    __syncthreads();
    #pragma unroll
    for (int it = 0; it < 2; ++it) {
        int idx = t + it * 256;
        int dl = idx >> 3, c8 = idx & 7;
        short8 s;
        #pragma unroll
        for (int e = 0; e < 8; ++e) s[e] = tile[c8 * 8 + e][dl];
        *(short8*)(vt + ((size_t)(b * 16 + n) * 64 + dl) * (size_t)KLENC + j0 + c8 * 8) = s;
    }
}

// ---------------------------------------------------------------------------
// Fused projection GEMMs (K, V, Q, RK) via global_load_lds, 128x128 tile, BK=32.
// LDS tiles XOR-swizzled: logical chunk c of row r at physical c ^ ((r>>1)&3).
// ---------------------------------------------------------------------------
__global__ __launch_bounds__(256, 3) void proj_gemm_kernel(
    const short* __restrict__ cat, const short* __restrict__ rin,
    const short* __restrict__ WqT, const short* __restrict__ WkT,
    const short* __restrict__ WvT, const short* __restrict__ WrT,
    const float* __restrict__ bq, const float* __restrict__ bk,
    const float* __restrict__ bv, const float* __restrict__ br,
    const float* __restrict__ rwb, const float* __restrict__ rrb,
    short* __restrict__ qw, short* __restrict__ qr,
    short* __restrict__ kb, short* __restrict__ vb, short* __restrict__ rk)
{
    __shared__ short As[128][32];
    __shared__ short Bs[128][32];

    const int lin = blockIdx.y * 8 + blockIdx.x;        // 0..767
    const int sw  = (lin & 7) * 96 + (lin >> 3);        // XCD-contiguous
    const int bx  = sw & 7;
    const int by  = sw >> 3;

    const short* A; const short* Bt; const float* bias; int yt, mode;
    if (by < 32)      { A = cat;                         Bt = WkT; bias = bk; yt = by;      mode = 0; }
    else if (by < 64) { A = cat;                         Bt = WvT; bias = bv; yt = by - 32; mode = 1; }
    else if (by < 80) { A = cat + (size_t)2048 * 1024;   Bt = WqT; bias = bq; yt = by - 64; mode = 2; }
    else              { A = rin;                         Bt = WrT; bias = br; yt = by - 80; mode = 3; }

    const int row0 = yt * 128, col0 = bx * 128;
    const int t = threadIdx.x;
    const int lane = t & 63, wid = t >> 6;
    const int row16 = lane & 15, g8 = lane >> 4;
    const int wr = wid >> 1, wc = wid & 1;

    f32x4 acc[4][4];
    #pragma unroll
    for (int m = 0; m < 4; ++m)
        #pragma unroll
        for (int nn = 0; nn < 4; ++nn)
            acc[m][nn] = (f32x4){0.f, 0.f, 0.f, 0.f};

    short* AsB = &As[0][0] + wid * 1024;
    short* BsB = &Bs[0][0] + wid * 1024;
    const int srow4 = lane >> 2;
    const int cs4 = (lane & 3) ^ ((lane >> 3) & 3);     // swizzled source chunk
    const short* Ag = A  + (size_t)(row0 + wid * 32 + srow4) * D_MODELC + cs4 * 8;
    const short* Bg = Bt + (size_t)(col0 + wid * 32 + srow4) * D_MODELC + cs4 * 8;
    const int xc2 = (row16 >> 1) & 3;                   // read-side xor

    for (int k0 = 0; k0 < D_MODELC; k0 += 32) {
        load_lds16(Ag + k0,              AsB);
        load_lds16(Ag + k0 + 16 * 1024,  AsB + 512);
        load_lds16(Bg + k0,              BsB);
        load_lds16(Bg + k0 + 16 * 1024,  BsB + 512);
        __syncthreads();
        short8 af[4], bfr[4];
        #pragma unroll
        for (int m = 0; m < 4; ++m)
            af[m] = *(const short8*)&As[wr * 64 + m * 16 + row16][(g8 ^ xc2) * 8];
        #pragma unroll
        for (int nn = 0; nn < 4; ++nn)
            bfr[nn] = *(const short8*)&Bs[wc * 64 + nn * 16 + row16][(g8 ^ xc2) * 8];
        #pragma unroll
        for (int m = 0; m < 4; ++m)
            #pragma unroll
            for (int nn = 0; nn < 4; ++nn)
                acc[m][nn] = MFMA16(af[m], bfr[nn], acc[m][nn]);
        __syncthreads();
    }

    float bvv[4], w1[4], w2[4];
    #pragma unroll
    for (int nn = 0; nn < 4; ++nn) {
        int c = col0 + wc * 64 + nn * 16 + row16;
        bvv[nn] = bias[c];
        w1[nn] = rwb[c];
        w2[nn] = rrb[c];
    }
    if (mode == 2) {
        #pragma unroll
        for (int m = 0; m < 4; ++m)
            #pragma unroll
            for (int nn = 0; nn < 4; ++nn) {
                int c = col0 + wc * 64 + nn * 16 + row16;
                #pragma unroll
                for (int reg = 0; reg < 4; ++reg) {
                    int r = row0 + wr * 64 + m * 16 + g8 * 4 + reg;
                    float v = acc[m][nn][reg] + bvv[nn];
                    qw[(size_t)r * D_MODELC + c] = (short)f2bf(v + w1[nn]);
                    qr[(size_t)r * D_MODELC + c] = (short)f2bf(v + w2[nn]);
                }
            }
    } else {
        short* C = (mode == 0) ? kb : (mode == 1) ? vb : rk;
        #pragma unroll
        for (int m = 0; m < 4; ++m)
            #pragma unroll
            for (int nn = 0; nn < 4; ++nn) {
                int c = col0 + wc * 64 + nn * 16 + row16;
                #pragma unroll
                for (int reg = 0; reg < 4; ++reg) {
                    int r = row0 + wr * 64 + m * 16 + g8 * 4 + reg;
                    C[(size_t)r * D_MODELC + c] = (short)f2bf(acc[m][nn][reg] + bvv[nn]);
                }
            }
    }
}

// ---------------------------------------------------------------------------
// Wo GEMM, split-K=2: fp32 partials (bias added in LN). Same swizzle as proj.
// ---------------------------------------------------------------------------
__global__ __launch_bounds__(256, 3) void wo_gemm_kernel(
    const short* __restrict__ A, const short* __restrict__ Bt,
    float* __restrict__ out0, float* __restrict__ out1)
{
    __shared__ short As[128][32];
    __shared__ short Bs[128][32];
    const int kz = blockIdx.z;
    float* C = kz ? out1 : out0;
    const int row0 = blockIdx.y * 128, col0 = blockIdx.x * 128;
    const int t = threadIdx.x;
    const int lane = t & 63, wid = t >> 6;
    const int row16 = lane & 15, g8 = lane >> 4;
    const int wr = wid >> 1, wc = wid & 1;

    f32x4 acc[4][4];
    #pragma unroll
    for (int m = 0; m < 4; ++m)
        #pragma unroll
        for (int nn = 0; nn < 4; ++nn)
            acc[m][nn] = (f32x4){0.f, 0.f, 0.f, 0.f};

    short* AsB = &As[0][0] + wid * 1024;
    short* BsB = &Bs[0][0] + wid * 1024;
    const int srow4 = lane >> 2;
    const int cs4 = (lane & 3) ^ ((lane >> 3) & 3);
    const short* Ag = A  + (size_t)(row0 + wid * 32 + srow4) * D_MODELC + cs4 * 8;
    const short* Bg = Bt + (size_t)(col0 + wid * 32 + srow4) * D_MODELC + cs4 * 8;
    const int xc2 = (row16 >> 1) & 3;

    const int kbase = kz * 512;
    for (int k0 = kbase; k0 < kbase + 512; k0 += 32) {
        load_lds16(Ag + k0,             AsB);
        load_lds16(Ag + k0 + 16 * 1024, AsB + 512);
        load_lds16(Bg + k0,             BsB);
        load_lds16(Bg + k0 + 16 * 1024, BsB + 512);
        __syncthreads();
        short8 af[4], bfr[4];
        #pragma unroll
        for (int m = 0; m < 4; ++m)
            af[m] = *(const short8*)&As[wr * 64 + m * 16 + row16][(g8 ^ xc2) * 8];
        #pragma unroll
        for (int nn = 0; nn < 4; ++nn)
            bfr[nn] = *(const short8*)&Bs[wc * 64 + nn * 16 + row16][(g8 ^ xc2) * 8];
        #pragma unroll
        for (int m = 0; m < 4; ++m)
            #pragma unroll
            for (int nn = 0; nn < 4; ++nn)
                acc[m][nn] = MFMA16(af[m], bfr[nn], acc[m][nn]);
        __syncthreads();
    }

    #pragma unroll
    for (int m = 0; m < 4; ++m)
        #pragma unroll
        for (int nn = 0; nn < 4; ++nn) {
            int c = col0 + wc * 64 + nn * 16 + row16;
            #pragma unroll
            for (int reg = 0; reg < 4; ++reg) {
                int r = row0 + wr * 64 + m * 16 + g8 * 4 + reg;
                C[(size_t)r * D_MODELC + c] = acc[m][nn][reg];
            }
        }
}

// ---------------------------------------------------------------------------
// LDS-staged MFMA flash attention, swapped-operand (S^T) softmax.
// Block = 64 q-rows (4 waves i-split) x one (b,n); K dbuf, V single, rk ring.
// AC^T = MFMA(K,Q), BD^T = MFMA(rk,Q): lane owns one q-row -> in-lane reduce.
// Defer-max (THR=8 in log2 domain) skips O-rescale on almost every step.
// ---------------------------------------------------------------------------
__global__ __launch_bounds__(256, 2) void attn_mfma_kernel(
    const short* __restrict__ qw, const short* __restrict__ qr,
    const short* __restrict__ kb, const short* __restrict__ rkb,
    const short* __restrict__ vt, short* __restrict__ av)
{
    __shared__ short Kl[2][64][64];      // 16 KB (dbuf)
    __shared__ short Vl[64][64];         // 8 KB  ([d][j])
    __shared__ short Rl[RINGC][64];      // 24 KB (rk ring, row = jr % 192)
    __shared__ short pun[4][1600];       // 12.5 KB/wave-union: bdT[80][20] then P[16][64]
    __shared__ float scb[4][16];         // sc / lsum broadcast

    const int wave = threadIdx.x >> 6, lane = threadIdx.x & 63;
    const int row16 = lane & 15, g8 = lane >> 4;
    const int srow = lane >> 3, chk = lane & 7;
    const int swz = srow & 7;            // staging source-chunk xor

    // balanced + XCD-contiguous remap: CU gets ic and 15-ic (pair sum uniform)
    const int lin = blockIdx.y * 16 + blockIdx.x;   // 0..511
    const int xcd = lin & 7;
    const int u   = lin >> 3;                        // 0..63
    const int v   = u & 31;
    const int bn  = xcd * 4 + (v >> 3);
    const int tt  = v & 7;
    const int ic  = (u >> 5) ? (15 - tt) : tt;
    const int b = bn & 1, n = bn >> 1;
    const int i0 = ic * 64;
    const int i0w = i0 + wave * 16;

    // Q fragments (row = i0w+row16, k = ks*32 + g8*8 + e)
    short8 qwf[2], qrf[2];
    #pragma unroll
    for (int ks = 0; ks < 2; ++ks) {
        size_t off = ((size_t)(i0w + row16) * 2 + b) * D_MODELC + n * 64 + ks * 32 + g8 * 8;
        qwf[ks] = *(const short8*)(qw + off);
        qrf[ks] = *(const short8*)(qr + off);
    }

    // ---- prologue: stage K(step0) and rk window(0) = [960-i0, 1088-i0) ----
    #pragma unroll
    for (int t = 0; t < 2; ++t) {
        int rr = wave * 16 + t * 8;
        int j  = rr + srow;
        int cs = chk ^ swz;
        load_lds16(kb + ((size_t)j * 2 + b) * D_MODELC + n * 64 + cs * 8, &Kl[0][rr][0]);
    }
    {
        const int p0 = 960 - i0;
        #pragma unroll
        for (int t = 0; t < 4; ++t) {
            int jrb_ = p0 + wave * 32 + t * 8;
            int slotb = jrb_ % RINGC;
            int jr = jrb_ + srow;
            int jc = jr < KLENC ? jr : KLENC - 1;
            int cs = chk ^ swz;
            load_lds16(rkb + (size_t)jc * D_MODELC + n * 64 + cs * 8, &Rl[slotb][0]);
        }
    }

    f32x4 accO[4];
    #pragma unroll
    for (int dt = 0; dt < 4; ++dt) accO[dt] = (f32x4){0.f, 0.f, 0.f, 0.f};
    float m = -INFINITY, lsum = 0.f;     // per-lane: q-row = i0w + row16 (log2 domain)

    const int T = (i0 + 63 + MEMLENC + 64) >> 6;
    const int r7 = row16 & 7;

    __syncthreads();

    for (int s = 0; s < T; ++s) {
        const int j0 = s * 64;
        const int cur = s & 1, nxt = cur ^ 1;

        // ---------- phase A: issue async staging ----------
        #pragma unroll
        for (int t = 0; t < 2; ++t) {             // K(s+1)
            int rr = wave * 16 + t * 8;
            int j  = j0 + 64 + rr + srow;
            if (j > KLENC - 1) j = KLENC - 1;
            int cs = chk ^ swz;
            load_lds16(kb + ((size_t)j * 2 + b) * D_MODELC + n * 64 + cs * 8, &Kl[nxt][rr][0]);
        }
        {
            const int nb = j0 + 1088 - i0;        // new rk rows for window(s+1)
            #pragma unroll
            for (int t = 0; t < 2; ++t) {
                int jrb_ = nb + wave * 16 + t * 8;
                int slotb = jrb_ % RINGC;
                int jr = jrb_ + srow;
                int jc = jr < KLENC ? jr : KLENC - 1;
                int cs = chk ^ swz;
                load_lds16(rkb + (size_t)jc * D_MODELC + n * 64 + cs * 8, &Rl[slotb][0]);
            }
        }
        #pragma unroll
        for (int t = 0; t < 2; ++t) {             // V(s), d-major
            int rr = wave * 16 + t * 8;
            int cs = chk ^ swz;
            load_lds16(vt + ((size_t)((b * 16 + n) * 64 + rr + srow)) * KLENC + j0 + cs * 8,
                       &Vl[rr][0]);
        }

        // ---------- AC^T = MFMA(K, Qw): lane holds j=g8*4+reg(+jt*16), i=row16 ----------
        f32x4 st[4];
        #pragma unroll
        for (int jt = 0; jt < 4; ++jt) {
            st[jt] = (f32x4){0.f, 0.f, 0.f, 0.f};
            const short* kr = &Kl[cur][jt * 16 + row16][0];
            st[jt] = MFMA16(*(const short8*)(kr + ((g8 ^ r7) * 8)),       qwf[0], st[jt]);
            st[jt] = MFMA16(*(const short8*)(kr + (((4 + g8) ^ r7) * 8)), qwf[1], st[jt]);
        }

        // ---------- BD^T over jr window from ring; store to bdT[jr_loc][i] ----------
        const int jrb_w = j0 - i0w + 1008;
        const int sb = jrb_w % RINGC;
        short* bdT = &pun[wave][0];
        #pragma unroll
        for (int rt = 0; rt < 5; ++rt) {
            int rsl = sb + rt * 16 + row16;
            if (rsl >= RINGC) rsl -= RINGC;
            const short* rr = &Rl[rsl][0];
            f32x4 bd = (f32x4){0.f, 0.f, 0.f, 0.f};
            bd = MFMA16(*(const short8*)(rr + ((g8 ^ r7) * 8)),       qrf[0], bd);
            bd = MFMA16(*(const short8*)(rr + (((4 + g8) ^ r7) * 8)), qrf[1], bd);
            #pragma unroll
            for (int e = 0; e < 4; ++e)
                bdT[(rt * 16 + g8 * 4 + e) * 20 + row16] = (short)f2bf(bd[e]);
        }

        // ---------- combine + mask (in-lane, 16 values per q-row) ----------
        float sl[4][4];
        #pragma unroll
        for (int jt = 0; jt < 4; ++jt)
            #pragma unroll
            for (int reg = 0; reg < 4; ++reg) {
                const int jl = jt * 16 + g8 * 4 + reg;
                float vv = st[jt][reg] + bf2f(bdT[(jl + 15 - row16) * 20 + row16]);
                sl[jt][reg] = (j0 + jl > i0w + row16 + MEMLENC) ? -INFINITY : vv * SL2C;
            }

        // ---------- in-lane max tree + 2 cross-lane steps ----------
        float mx0 = fmaxf(fmaxf(sl[0][0], sl[0][1]), fmaxf(sl[0][2], sl[0][3]));
        float mx1 = fmaxf(fmaxf(sl[1][0], sl[1][1]), fmaxf(sl[1][2], sl[1][3]));
        float mx2 = fmaxf(fmaxf(sl[2][0], sl[2][1]), fmaxf(sl[2][2], sl[2][3]));
        float mx3 = fmaxf(fmaxf(sl[3][0], sl[3][1]), fmaxf(sl[3][2], sl[3][3]));
        float mx = fmaxf(fmaxf(mx0, mx1), fmaxf(mx2, mx3));
        mx = fmaxf(mx, __shfl_xor(mx, 16, 64));
        mx = fmaxf(mx, __shfl_xor(mx, 32, 64));

        // ---------- defer-max rescale (rare) ----------
        if (__any(mx > m + 8.f)) {
            float mn = fmaxf(m, mx);
            float sc = exp2f(m - mn);            // first step: exp2(-inf)=0
            m = mn;
            lsum *= sc;
            if (lane < 16) scb[wave][lane] = sc;
            float4 s4 = *(const float4*)&scb[wave][g8 * 4];
            #pragma unroll
            for (int dt = 0; dt < 4; ++dt) {
                accO[dt][0] *= s4.x; accO[dt][1] *= s4.y;
                accO[dt][2] *= s4.z; accO[dt][3] *= s4.w;
            }
        }

        // ---------- P = exp2(S - m), in-lane sum, store P[i][j] swizzled ----------
        float ps = 0.f;
        #pragma unroll
        for (int jt = 0; jt < 4; ++jt)
            #pragma unroll
            for (int reg = 0; reg < 4; ++reg) {
                float p = exp2f(sl[jt][reg] - m);
                sl[jt][reg] = p;
                ps += p;
            }
        ps += __shfl_xor(ps, 16, 64);
        ps += __shfl_xor(ps, 32, 64);
        lsum += ps;
        short* pP = &pun[wave][0];               // overwrites bdT (reads done)
        #pragma unroll
        for (int jt = 0; jt < 4; ++jt)
            #pragma unroll
            for (int reg = 0; reg < 4; ++reg) {
                const int ch = (jt * 2 + (g8 >> 1)) ^ r7;
                pP[row16 * 64 + ch * 8 + (g8 & 1) * 4 + reg] = (short)f2bf(sl[jt][reg]);
            }

        __syncthreads();   // drains staging; Vl/Kl[nxt]/Rl-new now valid

        // ---------- PV: O += P @ V (accO rows = g8*4+reg, cols d = dt*16+row16) ----------
        #pragma unroll
        for (int ks2 = 0; ks2 < 2; ++ks2) {
            short8 pf = *(const short8*)&pP[row16 * 64 + (((ks2 * 4 + g8) ^ r7) * 8)];
            #pragma unroll
            for (int dt = 0; dt < 4; ++dt) {
                const short* vp = &Vl[dt * 16 + row16][(((ks2 * 4 + g8) ^ r7) * 8)];
                accO[dt] = MFMA16(pf, *(const short8*)vp, accO[dt]);
            }
        }

        __syncthreads();   // protect Vl/pun (restaged/overwritten next phase A)
    }

    // ---- epilogue: broadcast lsum to accO orientation, store ----
    if (lane < 16) scb[wave][lane] = lsum;
    float4 l4 = *(const float4*)&scb[wave][g8 * 4];
    float rl4[4] = {1.f / l4.x, 1.f / l4.y, 1.f / l4.z, 1.f / l4.w};
    #pragma unroll
    for (int dt = 0; dt < 4; ++dt)
        #pragma unroll
        for (int reg = 0; reg < 4; ++reg) {
            size_t o = ((size_t)(i0w + g8 * 4 + reg) * 2 + b) * D_MODELC + n * 64 + dt * 16 + row16;
            av[o] = (short)f2bf(accO[dt][reg] * rl4[reg]);
        }
}

// ---------------------------------------------------------------------------
// Residual + bias + LayerNorm: x = w + ao0 + ao1 + bo
// ---------------------------------------------------------------------------
__global__ __launch_bounds__(256) void ln_kernel(
    const float* __restrict__ w, const float* __restrict__ ao0,
    const float* __restrict__ ao1, const float* __restrict__ bo,
    const float* __restrict__ g, const float* __restrict__ bb,
    float* __restrict__ out)
{
    __shared__ float red[2][4];
    const int row = blockIdx.x;
    const int lane = threadIdx.x & 63;
    const int wv = threadIdx.x >> 6;
    const size_t base = (size_t)row * D_MODELC;
    const int c = threadIdx.x * 4;

    float4 xw = *(const float4*)&w[base + c];
    float4 x0 = *(const float4*)&ao0[base + c];
    float4 x1 = *(const float4*)&ao1[base + c];
    float4 xb = *(const float4*)&bo[c];
    float x[4] = {xw.x + x0.x + x1.x + xb.x, xw.y + x0.y + x1.y + xb.y,
                  xw.z + x0.z + x1.z + xb.z, xw.w + x0.w + x1.w + xb.w};

    float sum = x[0] + x[1] + x[2] + x[3];
    float ssq = x[0]*x[0] + x[1]*x[1] + x[2]*x[2] + x[3]*x[3];
    #pragma unroll
    for (int off = 32; off > 0; off >>= 1) {
        sum += __shfl_xor(sum, off, 64);
        ssq += __shfl_xor(ssq, off, 64);
    }
    if (lane == 0) { red[0][wv] = sum; red[1][wv] = ssq; }
    __syncthreads();
    sum = red[0][0] + red[0][1] + red[0][2] + red[0][3];
    ssq = red[1][0] + red[1][1] + red[1][2] + red[1][3];

    const float mu = sum * (1.0f / D_MODELC);
    const float var = ssq * (1.0f / D_MODELC) - mu * mu;
    const float rstd = rsqrtf(var + LN_EPSC);

    float4 o;
    o.x = (x[0] - mu) * rstd * g[c] + bb[c];
    o.y = (x[1] - mu) * rstd * g[c+1] + bb[c+1];
    o.z = (x[2] - mu) * rstd * g[c+2] + bb[c+2];
    o.w = (x[3] - mu) * rstd * g[c+3] + bb[c+3];
    *(float4*)&out[base + c] = o;
}

// ---------------------------------------------------------------------------
extern "C" void kernel_launch(void* const* d_in, const int* in_sizes, int n_in,
                              void* d_out, int out_size, void* d_ws, size_t ws_size,
                              hipStream_t stream)
{
    const float* w    = (const float*)d_in[0];
    const float* r    = (const float*)d_in[1];
    const float* mems = (const float*)d_in[2];
    const float* rwb  = (const float*)d_in[3];
    const float* rrb  = (const float*)d_in[4];
    // d_in[5] = attn_mask — deterministic causal+mem pattern, handled analytically
    const float* Wq = (const float*)d_in[6];
    const float* bq = (const float*)d_in[7];
    const float* Wk = (const float*)d_in[8];
    const float* bk = (const float*)d_in[9];
    const float* Wv = (const float*)d_in[10];
    const float* bv = (const float*)d_in[11];
    const float* Wr = (const float*)d_in[12];
    const float* br = (const float*)d_in[13];
    const float* Wo = (const float*)d_in[14];
    const float* bo = (const float*)d_in[15];
    const float* ln_g = (const float*)d_in[16];
    const float* ln_b = (const float*)d_in[17];
    float* out = (float*)d_out;

    char* ws = (char*)d_ws;
    const size_t MB = 1ull << 20;
    short* cat_bf = (short*)(ws + 0 * MB);    // [4096][1024] (8 MB)
    short* r_bf   = (short*)(ws + 8 * MB);    // [2048][1024] (4 MB)
    short* Wq_t   = (short*)(ws + 12 * MB);
    short* Wk_t   = (short*)(ws + 14 * MB);
    short* Wv_t   = (short*)(ws + 16 * MB);
    short* Wr_t   = (short*)(ws + 18 * MB);
    short* Wo_t   = (short*)(ws + 20 * MB);
    short* qw_bf  = (short*)(ws + 22 * MB);   // [2048][1024]
    short* qr_bf  = (short*)(ws + 26 * MB);
    short* k_bf   = (short*)(ws + 30 * MB);   // [4096][1024] (8 MB)
    short* v_bf   = (short*)(ws + 38 * MB);   // [4096][1024] (8 MB)
    short* rk_bf  = (short*)(ws + 46 * MB);   // [2048][1024]
    short* vt     = (short*)(ws + 50 * MB);   // [2][16][64][2048] (8 MB)
    short* av_bf  = (short*)(ws + 58 * MB);   // [2048][1024]
    float* ao0    = (float*)v_bf;             // v_bf dead after vtrans
    float* ao1    = (float*)k_bf;             // k_bf dead after attn

    dim3 blk(256);

    // casts
    cast_cat_kernel<<<dim3(2048), blk, 0, stream>>>(mems, w, 2048 * 1024, cat_bf);
    cast_cat_kernel<<<dim3(1024), blk, 0, stream>>>(r, r, 1 << 30, r_bf);

    // fused weight transposes
    tcast5_kernel<<<dim3(16, 16, 5), blk, 0, stream>>>(
        Wq, Wk, Wv, Wr, Wo, Wq_t, Wk_t, Wv_t, Wr_t, Wo_t);

    // fused projections (K, V, Q->qw/qr, RK)
    proj_gemm_kernel<<<dim3(8, 96), blk, 0, stream>>>(
        cat_bf, r_bf, Wq_t, Wk_t, Wv_t, Wr_t,
        bq, bk, bv, br, rwb, rrb,
        qw_bf, qr_bf, k_bf, v_bf, rk_bf);

    // V transpose
    vtrans_kernel<<<dim3(32, 32), blk, 0, stream>>>(v_bf, vt);

    // attention (LDS-staged, S^T softmax): grid 512
    attn_mfma_kernel<<<dim3(16, 32), blk, 0, stream>>>(
        qw_bf, qr_bf, k_bf, rk_bf, vt, av_bf);

    // output projection split-K (fp32 partials; bias in LN)
    wo_gemm_kernel<<<dim3(8, 16, 2), blk, 0, stream>>>(av_bf, Wo_t, ao0, ao1);

    // LN(w + ao0 + ao1 + bo)
    ln_kernel<<<dim3(2048), blk, 0, stream>>>(w, ao0, ao1, bo, ln_g, ln_b, out);
}